// Round 10
// baseline (333.831 us; speedup 1.0000x reference)
//
#include <hip/hip_runtime.h>
#include <math.h>

#define NP 16384      // pixels per map (128*128)
#define CH 256        // channels (K)
#define WDIM 128
#define EPSF 1e-8f

#define CHUNK 32
#define SPLITS 8
#define CPS (NP / SPLITS)            // 2048 cols per split
#define NCHUNK (CPS / CHUNK)         // 64
#define ROWS 256                     // rows per block (8 waves x 32)
#define NRT (NP / ROWS)              // 64 row tiles
#define CHUNK_BYTES (CHUNK * CH * 2) // 16384
#define NCOLSLOT (NRT * 3)           // 192 col-candidate slots per column

typedef short short8 __attribute__((ext_vector_type(8)));
typedef float floatx4 __attribute__((ext_vector_type(4)));

typedef __attribute__((address_space(1))) const unsigned int gu32;
typedef __attribute__((address_space(3))) unsigned int lu32;

#define NEG_INF_F __int_as_float(0xFF800000)

// ------------------------------------------------------------------
// prep: per-pixel 1/||d||, fp32 normalized transposed [pix][256],
// bf16 normalized swizzled (element ch stored at ch ^ ((pix&7)<<3))
// ------------------------------------------------------------------
__global__ __launch_bounds__(256) void prep_kernel(
    const float* __restrict__ A, const float* __restrict__ B,
    float* __restrict__ AT, float* __restrict__ BT,
    unsigned short* __restrict__ Abf, unsigned short* __restrict__ Bbf)
{
    __shared__ float tile[64 * 257];
    __shared__ float rnv[64];
    const int bid = blockIdx.x;
    const float* __restrict__ src = (bid < 256) ? A : B;
    float* __restrict__ dstT = (bid < 256) ? AT : BT;
    unsigned short* __restrict__ dstb = (bid < 256) ? Abf : Bbf;
    const int pixBase = (bid & 255) * 64;
    const int t = threadIdx.x;

    for (int k = 0; k < 64 * 256; k += 256) {
        int idx = k + t;
        int p = idx & 63;
        int c = idx >> 6;
        tile[p * 257 + c] = src[(size_t)c * NP + pixBase + p];
    }
    __syncthreads();
    if (t < 64) {
        float s = 0.f;
        for (int c = 0; c < 256; ++c) { float v = tile[t * 257 + c]; s = fmaf(v, v, s); }
        rnv[t] = 1.0f / sqrtf(s);
    }
    __syncthreads();
    for (int k = 0; k < 64 * 256; k += 256) {
        int idx = k + t;
        int p = idx >> 8;
        int c = idx & 255;
        dstT[((size_t)(pixBase + p) << 8) + c] = tile[p * 257 + c] * rnv[p];
    }
    for (int k = 0; k < 64 * 128; k += 256) {
        int idx = k + t;
        int p = idx >> 7;
        int c2 = (idx & 127) * 2;
        float rn = rnv[p];
        float v0 = tile[p * 257 + c2] * rn;
        float v1 = tile[p * 257 + c2 + 1] * rn;
        unsigned u0 = __float_as_uint(v0); u0 = (u0 + 0x7fffu + ((u0 >> 16) & 1u)) >> 16;
        unsigned u1 = __float_as_uint(v1); u1 = (u1 + 0x7fffu + ((u1 >> 16) & 1u)) >> 16;
        unsigned sw = ((unsigned)(p & 7)) << 3;
        int e = ((pixBase + p) << 8) + (c2 ^ (int)sw);
        *(unsigned*)(dstb + e) = (u0 & 0xffffu) | (u1 << 16);
    }
}

// ------------------------------------------------------------------
// simk ONE-PASS, 8-wave blocks (512 thr), R7 3-barrier merge structure.
// Per chunk: 32 MFMA/wave; row top-2 per lane; col per-lane sorted pair
// -> colbuf (padded) -> merge1 (512 thr, top-2 of 16) -> merge2 (32 thr,
// block top-3 per column -> global cand_col).
// Bfr[2][8]=64 VGPR pinned -> fits 128-reg cap -> 4 waves/SIMD.
// ------------------------------------------------------------------
__global__ __launch_bounds__(512, 4) void simk_kernel(
    const unsigned short* __restrict__ Abf, const unsigned short* __restrict__ Bbf,
    int* __restrict__ cand_row, unsigned* __restrict__ cand_col)
{
    __shared__ __align__(16) char smem[2 * CHUNK_BYTES];   // 32 KB staging
    __shared__ __align__(16) float colbuf[32 * 260];       // 33.3 KB (pad 260)
    __shared__ __align__(16) float2 colbuf2[32 * 18];      // 4.5 KB (pad 18)
    const int bid = blockIdx.x;
    const int rt = bid >> 3;
    const int split = bid & 7;
    const int t = threadIdx.x;     // 0..511
    const int w = t >> 6;          // 0..7
    const int l = t & 63;
    const int l15 = l & 15, lhi = l >> 4;   // lhi 0..3
    const int rowBase = rt * ROWS;
    const int colBase = split * CPS;

    // --- row-descriptor fragments (B-operand) from A, pinned: 2 ni x 8 kk ---
    short8 Bfr[2][8];
#pragma unroll
    for (int ni = 0; ni < 2; ++ni) {
        int pix = rowBase + w * 32 + ni * 16 + l15;
        const unsigned short* pr = Abf + ((size_t)pix << 8);
        int sw = (pix & 7) << 3;
#pragma unroll
        for (int kk = 0; kk < 8; ++kk) {
            int ke = kk * 32 + lhi * 8;
            Bfr[ni][kk] = *(const short8*)(pr + (ke ^ sw));
        }
    }
#pragma unroll
    for (int ni = 0; ni < 2; ++ni)
#pragma unroll
        for (int kk = 0; kk < 8; ++kk)
            asm volatile("" : "+v"(Bfr[ni][kk]));

    // --- LDS byte offsets for A-operand frags (mi=0; mi=1 is +8192) ---
    int aoff[8];
    {
        int cp = l15;
        int sw = (cp & 7) << 3;
#pragma unroll
        for (int kk = 0; kk < 8; ++kk) {
            int ke = kk * 32 + lhi * 8;
            aoff[kk] = (cp * 256 + (ke ^ sw)) * 2;
        }
    }

    float tv0[2], tv1[2];
#pragma unroll
    for (int ni = 0; ni < 2; ++ni) { tv0[ni] = NEG_INF_F; tv1[ni] = NEG_INF_F; }

    const char* gbase = (const char*)(Bbf + ((size_t)colBase << 8));
    const floatx4 fzero = {0.f, 0.f, 0.f, 0.f};
    floatx4 acc[2][2];

#define STAGE(CIDX, BUFSEL) do {                                              \
        const char* gsrc_ = gbase + (size_t)(CIDX) * CHUNK_BYTES;             \
        char* bdst_ = smem + (BUFSEL) * CHUNK_BYTES;                          \
        _Pragma("unroll")                                                     \
        for (int r_ = 0; r_ < 2; ++r_) {                                      \
            int off_ = w * 2048 + r_ * 1024;                                  \
            __builtin_amdgcn_global_load_lds((gu32*)(gsrc_ + off_ + l * 16),  \
                                             (lu32*)(bdst_ + off_), 16, 0, 0);\
        }                                                                     \
    } while (0)

    STAGE(0, 0);

    for (int c = 0; c < NCHUNK; ++c) {
        __syncthreads();               // chunk c staged; colbuf free
        if (c + 1 < NCHUNK) STAGE(c + 1, (c + 1) & 1);

        // ---- COMPUTE: 32 MFMA into acc ----
        {
            const char* buf = smem + (c & 1) * CHUNK_BYTES;
            __builtin_amdgcn_s_setprio(1);
            {
                short8 a0 = *(const short8*)(buf + aoff[0]);
                short8 a1 = *(const short8*)(buf + aoff[0] + 8192);
#pragma unroll
                for (int ni = 0; ni < 2; ++ni) {
                    acc[0][ni] = __builtin_amdgcn_mfma_f32_16x16x32_bf16(a0, Bfr[ni][0], fzero, 0, 0, 0);
                    acc[1][ni] = __builtin_amdgcn_mfma_f32_16x16x32_bf16(a1, Bfr[ni][0], fzero, 0, 0, 0);
                }
            }
#pragma unroll
            for (int kk = 1; kk < 8; ++kk) {
                short8 a0 = *(const short8*)(buf + aoff[kk]);
                short8 a1 = *(const short8*)(buf + aoff[kk] + 8192);
#pragma unroll
                for (int ni = 0; ni < 2; ++ni) {
                    acc[0][ni] = __builtin_amdgcn_mfma_f32_16x16x32_bf16(a0, Bfr[ni][kk], acc[0][ni], 0, 0, 0);
                    acc[1][ni] = __builtin_amdgcn_mfma_f32_16x16x32_bf16(a1, Bfr[ni][kk], acc[1][ni], 0, 0, 0);
                }
            }
            __builtin_amdgcn_s_setprio(0);
        }

        // ---- COL extract: per-lane sorted pair (ni=2) -> colbuf ----
        {
            const unsigned brb = ((unsigned)w << 5) | (unsigned)l15;
#pragma unroll
            for (int mi = 0; mi < 2; ++mi) {
#pragma unroll
                for (int reg = 0; reg < 4; ++reg) {
                    unsigned k0 = (__float_as_uint(acc[mi][0][reg]) & 0xFFFFF000u) | brb;
                    unsigned k1 = (__float_as_uint(acc[mi][1][reg]) & 0xFFFFF000u) | (brb | 16u);
                    float f0 = __uint_as_float(k0), f1 = __uint_as_float(k1);
                    float hi = fmaxf(f0, f1), lo = fminf(f0, f1);
                    int colL = mi * 16 + lhi * 4 + reg;
                    *(float2*)&colbuf[colL * 260 + w * 32 + l15 * 2] = make_float2(hi, lo);
                }
            }
        }

        // ---- ROW top-2 (packed key | c*32 + col-local) ----
        {
            const int cS = c << 5;
#pragma unroll
            for (int mi = 0; mi < 2; ++mi) {
#pragma unroll
                for (int reg = 0; reg < 4; ++reg) {
                    const int ib = (lhi * 4 + mi * 16 + reg) | cS;
#pragma unroll
                    for (int ni = 0; ni < 2; ++ni) {
                        int kb = (__float_as_int(acc[mi][ni][reg]) & 0xFFFFF000) | ib;
                        float fk = __int_as_float(kb);
                        float h = fmaxf(tv0[ni], fk);
                        float lo2 = fminf(tv0[ni], fk);
                        tv0[ni] = h;
                        tv1[ni] = fmaxf(tv1[ni], lo2);
                    }
                }
            }
        }

        __syncthreads();               // colbuf complete
        // ---- merge1: 512 threads, (col, grp of 16 slots) -> top-2 ----
        {
            int colL = t >> 4, grp = t & 15;
            const float4* p4 = (const float4*)&colbuf[colL * 260 + grp * 16];
            float a = NEG_INF_F, b = NEG_INF_F;
#pragma unroll
            for (int q = 0; q < 4; ++q) {
                float4 v = p4[q];
                float h, lo;
                h = fmaxf(a, v.x); lo = fminf(a, v.x); a = h; b = fmaxf(b, lo);
                h = fmaxf(a, v.y); lo = fminf(a, v.y); a = h; b = fmaxf(b, lo);
                h = fmaxf(a, v.z); lo = fminf(a, v.z); a = h; b = fmaxf(b, lo);
                h = fmaxf(a, v.w); lo = fminf(a, v.w); a = h; b = fmaxf(b, lo);
            }
            colbuf2[colL * 18 + grp] = make_float2(a, b);
        }
        __syncthreads();               // colbuf2 complete
        // ---- merge2: 32 threads: block top-3 of 32 keys -> cand_col ----
        if (t < 32) {
            float b0 = NEG_INF_F, b1 = NEG_INF_F, b2 = NEG_INF_F;
#pragma unroll
            for (int j = 0; j < 16; ++j) {
                float2 v = colbuf2[t * 18 + j];
                float k = v.x, h;
                h = fmaxf(b0, k); k = fminf(b0, k); b0 = h;
                h = fmaxf(b1, k); k = fminf(b1, k); b1 = h;
                b2 = fmaxf(b2, k);
                k = v.y;
                h = fmaxf(b0, k); k = fminf(b0, k); b0 = h;
                h = fmaxf(b1, k); k = fminf(b1, k); b1 = h;
                b2 = fmaxf(b2, k);
            }
            int colG = colBase + c * 32 + t;
            cand_col[(size_t)(rt * 3 + 0) * NP + colG] = __float_as_uint(b0);
            cand_col[(size_t)(rt * 3 + 1) * NP + colG] = __float_as_uint(b1);
            cand_col[(size_t)(rt * 3 + 2) * NP + colG] = __float_as_uint(b2);
        }
    }
#undef STAGE

    // ---- final row merge: 8 keys per row -> top-3 per split ----
    __syncthreads();
    int2* mrg = (int2*)colbuf;         // [256 rows][4 lhi]
#pragma unroll
    for (int ni = 0; ni < 2; ++ni) {
        int rloc = w * 32 + ni * 16 + l15;
        int2 p;
        p.x = __float_as_int(tv0[ni]);
        p.y = __float_as_int(tv1[ni]);
        mrg[rloc * 4 + lhi] = p;
    }
    __syncthreads();
    if (t < 256) {
        float b0 = NEG_INF_F, b1 = NEG_INF_F, b2 = NEG_INF_F;
#pragma unroll
        for (int q = 0; q < 4; ++q) {
            int2 p = mrg[t * 4 + q];
            int ks[2] = {p.x, p.y};
#pragma unroll
            for (int j = 0; j < 2; ++j) {
                float k = __int_as_float(ks[j]), h;
                h = fmaxf(b0, k); k = fminf(b0, k); b0 = h;
                h = fmaxf(b1, k); k = fminf(b1, k); b1 = h;
                b2 = fmaxf(b2, k);
            }
        }
        int rowG = rowBase + t;
        int* o = cand_row + (size_t)rowG * 24 + split * 3;
        o[0] = colBase + (__float_as_int(b0) & 0xFFF);
        o[1] = colBase + (__float_as_int(b1) & 0xFFF);
        o[2] = colBase + (__float_as_int(b2) & 0xFFF);
    }
}

// ------------------------------------------------------------------
// mergecol: per column, bf16-key top-6 of 192 block partials -> rows
// ------------------------------------------------------------------
__global__ __launch_bounds__(256) void mergecol_kernel(
    const unsigned* __restrict__ cand_col, int* __restrict__ col6)
{
    int col = blockIdx.x * 256 + threadIdx.x;   // 0..16383
    float bv0 = NEG_INF_F, bv1 = NEG_INF_F, bv2 = NEG_INF_F;
    float bv3 = NEG_INF_F, bv4 = NEG_INF_F, bv5 = NEG_INF_F;
    for (int s = 0; s < NCOLSLOT; ++s) {
        float k = __uint_as_float(cand_col[(size_t)s * NP + col]);
        float h;
        h = fmaxf(bv0, k); k = fminf(bv0, k); bv0 = h;
        h = fmaxf(bv1, k); k = fminf(bv1, k); bv1 = h;
        h = fmaxf(bv2, k); k = fminf(bv2, k); bv2 = h;
        h = fmaxf(bv3, k); k = fminf(bv3, k); bv3 = h;
        h = fmaxf(bv4, k); k = fminf(bv4, k); bv4 = h;
        bv5 = fmaxf(bv5, k);
    }
    const float thr = bv5;
    int r0 = 0, r1 = 0, r2 = 0, r3 = 0, r4 = 0, r5 = 0;
    int cnt = 0;
    for (int s = 0; s < NCOLSLOT; ++s) {
        unsigned ku = cand_col[(size_t)s * NP + col];
        float k = __uint_as_float(ku);
        bool take = (k >= thr) && (cnt < 6);
        int row = (s / 3) * 256 + (int)(ku & 0xFFu);
        r0 = (take && cnt == 0) ? row : r0;
        r1 = (take && cnt == 1) ? row : r1;
        r2 = (take && cnt == 2) ? row : r2;
        r3 = (take && cnt == 3) ? row : r3;
        r4 = (take && cnt == 4) ? row : r4;
        r5 = (take && cnt == 5) ? row : r5;
        cnt += take ? 1 : 0;
    }
    int* o = col6 + (size_t)col * 6;
    o[0] = r0; o[1] = r1; o[2] = r2; o[3] = r3; o[4] = r4; o[5] = r5;
}

// ------------------------------------------------------------------
// rescore_row: exact fp32 top-2 over 24 cands per row (wave per row)
// ------------------------------------------------------------------
__global__ __launch_bounds__(256) void rescore_row_kernel(
    const float* __restrict__ AT, const float* __restrict__ BT,
    const int* __restrict__ cand_row, float4* __restrict__ final12)
{
    const int t = threadIdx.x;
    const int w = t >> 6, l = t & 63;
    const int row = blockIdx.x * 4 + w;    // 0..16383
    float4 rv = *(const float4*)(AT + ((size_t)row << 8) + l * 4);
    float v0 = -4.f, v1 = -4.f; int i0 = 0x7fffffff, i1 = 0x7fffffff;
    const int* __restrict__ cl = cand_row + (size_t)row * 24;
#pragma unroll 4
    for (int j = 0; j < 24; ++j) {
        int idx = cl[j];
        float4 cv = *(const float4*)(BT + ((size_t)idx << 8) + l * 4);
        float d = rv.x * cv.x;
        d = fmaf(rv.y, cv.y, d);
        d = fmaf(rv.z, cv.z, d);
        d = fmaf(rv.w, cv.w, d);
#pragma unroll
        for (int m = 1; m < 64; m <<= 1) d += __shfl_xor(d, m, 64);
        if (d > v0 || (d == v0 && idx < i0)) {
            v1 = v0; i1 = i0; v0 = d; i0 = idx;
        } else if (d > v1 || (d == v1 && idx < i1)) {
            v1 = d; i1 = idx;
        }
    }
    if (l == 0) {
        float4 r; r.x = v0; r.y = v1;
        r.z = __int_as_float(i0); r.w = __int_as_float(i1);
        final12[row] = r;
    }
}

// ------------------------------------------------------------------
// rescore_col: exact fp32 top-2 over 6 cands per column (wave per col)
// ------------------------------------------------------------------
__global__ __launch_bounds__(256) void rescore_col_kernel(
    const float* __restrict__ AT, const float* __restrict__ BT,
    const int* __restrict__ col6,
    int* __restrict__ nn21, float* __restrict__ ratio21)
{
    const int t = threadIdx.x;
    const int w = t >> 6, l = t & 63;
    const int col = blockIdx.x * 4 + w;    // 0..16383
    float4 rv = *(const float4*)(BT + ((size_t)col << 8) + l * 4);
    float v0 = -4.f, v1 = -4.f; int i0 = 0x7fffffff, i1 = 0x7fffffff;
    const int* __restrict__ cl = col6 + (size_t)col * 6;
#pragma unroll
    for (int j = 0; j < 6; ++j) {
        int idx = cl[j];
        float4 cv = *(const float4*)(AT + ((size_t)idx << 8) + l * 4);
        float d = rv.x * cv.x;
        d = fmaf(rv.y, cv.y, d);
        d = fmaf(rv.z, cv.z, d);
        d = fmaf(rv.w, cv.w, d);
#pragma unroll
        for (int m = 1; m < 64; m <<= 1) d += __shfl_xor(d, m, 64);
        if (d > v0 || (d == v0 && idx < i0)) {
            v1 = v0; i1 = i0; v0 = d; i0 = idx;
        } else if (d > v1 || (d == v1 && idx < i1)) {
            v1 = d; i1 = idx;
        }
    }
    if (l == 0) {
        nn21[col] = i0;
        float d0 = sqrtf(fmaxf(2.f - 2.f * v0, 1e-12f));
        float d1 = sqrtf(fmaxf(2.f - 2.f * v1, 1e-12f));
        ratio21[col] = d0 / (d1 + EPSF);
    }
}

// ------------------------------------------------------------------
// final: mutual check, ratio test, border mask
// ------------------------------------------------------------------
__global__ void final_kernel(const float4* __restrict__ final12,
                             const int* __restrict__ nn21,
                             const float* __restrict__ ratio21,
                             float* __restrict__ out) {
    int i = blockIdx.x * blockDim.x + threadIdx.x;  // 0..16383
    float4 a = final12[i];
    float d0 = sqrtf(fmaxf(2.f - 2.f * a.x, 1e-12f));
    float d1 = sqrtf(fmaxf(2.f - 2.f * a.y, 1e-12f));
    int nn = __float_as_int(a.z);
    float r12 = d0 / (d1 + EPSF);
    bool mutual = (nn21[nn] == i);
    float r = fmaxf(r12, ratio21[nn]);
    int xA = i & (WDIM - 1), yA = i >> 7;
    int xB = nn & (WDIM - 1), yB = nn >> 7;
    bool border = (xA == 0) || (xA == WDIM - 1) || (yA == 0) || (yA == WDIM - 1) ||
                  (xB == 0) || (xB == WDIM - 1) || (yB == 0) || (yB == WDIM - 1);
    bool valid = mutual && (r < 0.95f) && !border;
    out[2 * i]       = valid ? d0 : 0.f;
    out[2 * i + 1]   = valid ? d1 : 0.f;
    out[2 * NP + i]  = (float)nn;
    out[3 * NP + i]  = valid ? 1.f : 0.f;
}

extern "C" void kernel_launch(void* const* d_in, const int* in_sizes, int n_in,
                              void* d_out, int out_size, void* d_ws, size_t ws_size,
                              hipStream_t stream) {
    (void)in_sizes; (void)n_in; (void)out_size; (void)ws_size;
    const float* A = (const float*)d_in[0];
    const float* B = (const float*)d_in[1];
    float* out = (float*)d_out;

    char* ws = (char*)d_ws;
    float* AT = (float*)ws;                                          // 16 MB
    float* BT = AT + (size_t)NP * CH;                                // 16 MB
    unsigned short* Abf = (unsigned short*)(BT + (size_t)NP * CH);   // 8 MB
    unsigned short* Bbf = Abf + (size_t)NP * CH;                     // 8 MB
    int* cand_row = (int*)(Bbf + (size_t)NP * CH);                   // 1.5 MB
    unsigned* cand_col = (unsigned*)(cand_row + (size_t)NP * 24);    // 12.6 MB
    int* col6 = (int*)(cand_col + (size_t)NCOLSLOT * NP);            // 0.4 MB
    float4* final12 = (float4*)(col6 + (size_t)NP * 6);              // 256 KB
    int* nn21 = (int*)(final12 + NP);                                // 64 KB
    float* ratio21 = (float*)(nn21 + NP);                            // 64 KB

    prep_kernel<<<512, 256, 0, stream>>>(A, B, AT, BT, Abf, Bbf);
    simk_kernel<<<NRT * SPLITS, 512, 0, stream>>>(Abf, Bbf, cand_row, cand_col);
    mergecol_kernel<<<NP / 256, 256, 0, stream>>>(cand_col, col6);
    rescore_row_kernel<<<NP / 4, 256, 0, stream>>>(AT, BT, cand_row, final12);
    rescore_col_kernel<<<NP / 4, 256, 0, stream>>>(AT, BT, col6, nn21, ratio21);
    final_kernel<<<NP / 256, 256, 0, stream>>>(final12, nn21, ratio21, out);
}

// Round 11
// 294.388 us; speedup vs baseline: 1.1340x; 1.1340x over previous
//
#include <hip/hip_runtime.h>
#include <math.h>

#define NP 16384      // pixels per map (128*128)
#define CH 256        // channels (K)
#define WDIM 128
#define EPSF 1e-8f

#define CHUNK 32
#define SPLITS 8
#define CPS (NP / SPLITS)            // 2048 cols per split
#define NCHUNK (CPS / CHUNK)         // 64
#define ROWS 256                     // rows per block (4 waves x 64)
#define NRT (NP / ROWS)              // 64 row tiles
#define CHUNK_BYTES (CHUNK * CH * 2) // 16384
#define NCOLSLOT (NRT * 3)           // 192 col-candidate slots per column
#define CBSTRIDE 262                 // colbuf row stride in floats (== 6 mod 32)

typedef short short8 __attribute__((ext_vector_type(8)));
typedef float floatx4 __attribute__((ext_vector_type(4)));

typedef __attribute__((address_space(1))) const unsigned int gu32;
typedef __attribute__((address_space(3))) unsigned int lu32;

#define NEG_INF_F __int_as_float(0xFF800000)

// ------------------------------------------------------------------
// prep: per-pixel 1/||d||, fp32 normalized transposed [pix][256],
// bf16 normalized swizzled (element ch stored at ch ^ ((pix&7)<<3))
// ------------------------------------------------------------------
__global__ __launch_bounds__(256) void prep_kernel(
    const float* __restrict__ A, const float* __restrict__ B,
    float* __restrict__ AT, float* __restrict__ BT,
    unsigned short* __restrict__ Abf, unsigned short* __restrict__ Bbf)
{
    __shared__ float tile[64 * 257];
    __shared__ float rnv[64];
    const int bid = blockIdx.x;
    const float* __restrict__ src = (bid < 256) ? A : B;
    float* __restrict__ dstT = (bid < 256) ? AT : BT;
    unsigned short* __restrict__ dstb = (bid < 256) ? Abf : Bbf;
    const int pixBase = (bid & 255) * 64;
    const int t = threadIdx.x;

    for (int k = 0; k < 64 * 256; k += 256) {
        int idx = k + t;
        int p = idx & 63;
        int c = idx >> 6;
        tile[p * 257 + c] = src[(size_t)c * NP + pixBase + p];
    }
    __syncthreads();
    if (t < 64) {
        float s = 0.f;
        for (int c = 0; c < 256; ++c) { float v = tile[t * 257 + c]; s = fmaf(v, v, s); }
        rnv[t] = 1.0f / sqrtf(s);
    }
    __syncthreads();
    for (int k = 0; k < 64 * 256; k += 256) {
        int idx = k + t;
        int p = idx >> 8;
        int c = idx & 255;
        dstT[((size_t)(pixBase + p) << 8) + c] = tile[p * 257 + c] * rnv[p];
    }
    for (int k = 0; k < 64 * 128; k += 256) {
        int idx = k + t;
        int p = idx >> 7;
        int c2 = (idx & 127) * 2;
        float rn = rnv[p];
        float v0 = tile[p * 257 + c2] * rn;
        float v1 = tile[p * 257 + c2 + 1] * rn;
        unsigned u0 = __float_as_uint(v0); u0 = (u0 + 0x7fffu + ((u0 >> 16) & 1u)) >> 16;
        unsigned u1 = __float_as_uint(v1); u1 = (u1 + 0x7fffu + ((u1 >> 16) & 1u)) >> 16;
        unsigned sw = ((unsigned)(p & 7)) << 3;
        int e = ((pixBase + p) << 8) + (c2 ^ (int)sw);
        *(unsigned*)(dstb + e) = (u0 & 0xffffu) | (u1 << 16);
    }
}

// ------------------------------------------------------------------
// simk ONE-PASS, 2 barriers/chunk (R7 base):
//  - merge2 deferred one chunk (colbuf2 double-buffered), runs after the
//    loop-top barrier overlapped with STAGE+COMPUTE
//  - merge1 reads interleaved slots (s = g + 8k) as b64 -> ~3-way banks
// Per chunk: 64 MFMA/wave; row top-2/lane; col per-lane sorted pair
// -> colbuf(262-stride) -> merge1 (8 thr/col, top-2 of 16 pairs)
// -> colbuf2[c&1] -> (next chunk) merge2: block top-3/col -> cand_col.
// ------------------------------------------------------------------
__global__ __launch_bounds__(256, 2) void simk_kernel(
    const unsigned short* __restrict__ Abf, const unsigned short* __restrict__ Bbf,
    int* __restrict__ cand_row, unsigned* __restrict__ cand_col)
{
    __shared__ __align__(16) char smem[2 * CHUNK_BYTES];   // 32 KB staging
    __shared__ __align__(16) float colbuf[32 * CBSTRIDE];  // 33.5 KB
    __shared__ __align__(16) float2 colbuf2[2][32][9];     // 4.6 KB (dbuf)
    const int bid = blockIdx.x;
    const int rt = bid >> 3;
    const int split = bid & 7;
    const int t = threadIdx.x;
    const int w = t >> 6;
    const int l = t & 63;
    const int l15 = l & 15, lhi = l >> 4;
    const int rowBase = rt * ROWS;
    const int colBase = split * CPS;

    // --- row-descriptor fragments (B-operand) from A, pinned ---
    short8 Bfr[4][8];
#pragma unroll
    for (int ni = 0; ni < 4; ++ni) {
        int pix = rowBase + w * 64 + ni * 16 + l15;
        const unsigned short* pr = Abf + ((size_t)pix << 8);
        int sw = (pix & 7) << 3;
#pragma unroll
        for (int kk = 0; kk < 8; ++kk) {
            int ke = kk * 32 + lhi * 8;
            Bfr[ni][kk] = *(const short8*)(pr + (ke ^ sw));
        }
    }
#pragma unroll
    for (int ni = 0; ni < 4; ++ni)
#pragma unroll
        for (int kk = 0; kk < 8; ++kk)
            asm volatile("" : "+v"(Bfr[ni][kk]));

    // --- LDS byte offsets for A-operand frags (mi=0; mi=1 is +8192) ---
    int aoff[8];
    {
        int cp = l15;
        int sw = (cp & 7) << 3;
#pragma unroll
        for (int kk = 0; kk < 8; ++kk) {
            int ke = kk * 32 + lhi * 8;
            aoff[kk] = (cp * 256 + (ke ^ sw)) * 2;
        }
    }

    float tv0[4], tv1[4];
#pragma unroll
    for (int ni = 0; ni < 4; ++ni) { tv0[ni] = NEG_INF_F; tv1[ni] = NEG_INF_F; }

    const char* gbase = (const char*)(Bbf + ((size_t)colBase << 8));
    const floatx4 fzero = {0.f, 0.f, 0.f, 0.f};
    floatx4 acc[2][4];

#define STAGE(CIDX, BUFSEL) do {                                              \
        const char* gsrc_ = gbase + (size_t)(CIDX) * CHUNK_BYTES;             \
        char* bdst_ = smem + (BUFSEL) * CHUNK_BYTES;                          \
        _Pragma("unroll")                                                     \
        for (int r_ = 0; r_ < 4; ++r_) {                                      \
            int off_ = w * 4096 + r_ * 1024;                                  \
            __builtin_amdgcn_global_load_lds((gu32*)(gsrc_ + off_ + l * 16),  \
                                             (lu32*)(bdst_ + off_), 16, 0, 0);\
        }                                                                     \
    } while (0)

// block top-3 per column of chunk CIDX from colbuf2[(CIDX)&1] -> cand_col
#define MERGE2(CIDX) do {                                                     \
        if (t < 32) {                                                         \
            float b0_ = NEG_INF_F, b1_ = NEG_INF_F, b2_ = NEG_INF_F;          \
            _Pragma("unroll")                                                 \
            for (int j_ = 0; j_ < 8; ++j_) {                                  \
                float2 v_ = colbuf2[(CIDX) & 1][t][j_];                       \
                float k_ = v_.x, h_;                                          \
                h_ = fmaxf(b0_, k_); k_ = fminf(b0_, k_); b0_ = h_;           \
                h_ = fmaxf(b1_, k_); k_ = fminf(b1_, k_); b1_ = h_;           \
                b2_ = fmaxf(b2_, k_);                                         \
                k_ = v_.y;                                                    \
                h_ = fmaxf(b0_, k_); k_ = fminf(b0_, k_); b0_ = h_;           \
                h_ = fmaxf(b1_, k_); k_ = fminf(b1_, k_); b1_ = h_;           \
                b2_ = fmaxf(b2_, k_);                                         \
            }                                                                 \
            int colG_ = colBase + (CIDX) * 32 + t;                            \
            cand_col[(size_t)(rt * 3 + 0) * NP + colG_] = __float_as_uint(b0_);\
            cand_col[(size_t)(rt * 3 + 1) * NP + colG_] = __float_as_uint(b1_);\
            cand_col[(size_t)(rt * 3 + 2) * NP + colG_] = __float_as_uint(b2_);\
        }                                                                     \
    } while (0)

    STAGE(0, 0);

    for (int c = 0; c < NCHUNK; ++c) {
        __syncthreads();   // B1: staging(c) ready; colbuf free; colbuf2[(c-1)&1] published
        if (c + 1 < NCHUNK) STAGE(c + 1, (c + 1) & 1);
        if (c > 0) MERGE2(c - 1);

        // ---- COMPUTE: 64 MFMA into acc ----
        {
            const char* buf = smem + (c & 1) * CHUNK_BYTES;
            __builtin_amdgcn_s_setprio(1);
            {
                short8 a0 = *(const short8*)(buf + aoff[0]);
                short8 a1 = *(const short8*)(buf + aoff[0] + 8192);
#pragma unroll
                for (int ni = 0; ni < 4; ++ni) {
                    acc[0][ni] = __builtin_amdgcn_mfma_f32_16x16x32_bf16(a0, Bfr[ni][0], fzero, 0, 0, 0);
                    acc[1][ni] = __builtin_amdgcn_mfma_f32_16x16x32_bf16(a1, Bfr[ni][0], fzero, 0, 0, 0);
                }
            }
#pragma unroll
            for (int kk = 1; kk < 8; ++kk) {
                short8 a0 = *(const short8*)(buf + aoff[kk]);
                short8 a1 = *(const short8*)(buf + aoff[kk] + 8192);
#pragma unroll
                for (int ni = 0; ni < 4; ++ni) {
                    acc[0][ni] = __builtin_amdgcn_mfma_f32_16x16x32_bf16(a0, Bfr[ni][kk], acc[0][ni], 0, 0, 0);
                    acc[1][ni] = __builtin_amdgcn_mfma_f32_16x16x32_bf16(a1, Bfr[ni][kk], acc[1][ni], 0, 0, 0);
                }
            }
            __builtin_amdgcn_s_setprio(0);
        }

        // ---- COL extract: per-lane sorted pair of 4 rows -> colbuf ----
        {
            const unsigned brb = ((unsigned)w << 6) | (unsigned)l15;
#pragma unroll
            for (int mi = 0; mi < 2; ++mi) {
#pragma unroll
                for (int reg = 0; reg < 4; ++reg) {
                    unsigned k0 = (__float_as_uint(acc[mi][0][reg]) & 0xFFFFF000u) | brb;
                    unsigned k1 = (__float_as_uint(acc[mi][1][reg]) & 0xFFFFF000u) | (brb | 16u);
                    unsigned k2 = (__float_as_uint(acc[mi][2][reg]) & 0xFFFFF000u) | (brb | 32u);
                    unsigned k3 = (__float_as_uint(acc[mi][3][reg]) & 0xFFFFF000u) | (brb | 48u);
                    float f0 = __uint_as_float(k0), f1 = __uint_as_float(k1);
                    float f2 = __uint_as_float(k2), f3 = __uint_as_float(k3);
                    float h01 = fmaxf(f0, f1), l01 = fminf(f0, f1);
                    float h23 = fmaxf(f2, f3), l23 = fminf(f2, f3);
                    float hi = fmaxf(h01, h23);
                    float lo = fmaxf(fminf(h01, h23), fmaxf(l01, l23));
                    int colL = mi * 16 + lhi * 4 + reg;
                    *(float2*)&colbuf[colL * CBSTRIDE + w * 32 + l15 * 2] = make_float2(hi, lo);
                }
            }
        }

        // ---- ROW top-2 (packed key | c*32 + col-local) ----
        {
            const int cS = c << 5;
#pragma unroll
            for (int mi = 0; mi < 2; ++mi) {
#pragma unroll
                for (int reg = 0; reg < 4; ++reg) {
                    const int ib = (lhi * 4 + mi * 16 + reg) | cS;
#pragma unroll
                    for (int ni = 0; ni < 4; ++ni) {
                        int kb = (__float_as_int(acc[mi][ni][reg]) & 0xFFFFF000) | ib;
                        float fk = __int_as_float(kb);
                        float h = fmaxf(tv0[ni], fk);
                        float lo2 = fminf(tv0[ni], fk);
                        tv0[ni] = h;
                        tv1[ni] = fmaxf(tv1[ni], lo2);
                    }
                }
            }
        }

        __syncthreads();   // B2: colbuf complete
        // ---- merge1: 8 thr/col, interleaved slots s = g+8k (b64, ~3-way) ----
        {
            int col = t >> 3, g = t & 7;
            float a = NEG_INF_F, b = NEG_INF_F;
#pragma unroll
            for (int k = 0; k < 16; ++k) {
                float2 v = *(const float2*)&colbuf[col * CBSTRIDE + 2 * (g + (k << 3))];
                float t0 = fmaxf(a, v.x);
                float t1 = fmaxf(fminf(a, v.x), fmaxf(b, v.y));
                a = t0; b = t1;
            }
            colbuf2[c & 1][col][g] = make_float2(a, b);
        }
    }
    __syncthreads();       // publishes colbuf2[(NCHUNK-1)&1]; colbuf free
    MERGE2(NCHUNK - 1);
#undef STAGE
#undef MERGE2

    // ---- final row merge: 8 keys per row -> top-2 per split ----
    int2* mrg = (int2*)colbuf;     // [256 rows][4 lhi]
#pragma unroll
    for (int ni = 0; ni < 4; ++ni) {
        int rloc = w * 64 + ni * 16 + l15;
        int2 p;
        p.x = __float_as_int(tv0[ni]);
        p.y = __float_as_int(tv1[ni]);
        mrg[rloc * 4 + lhi] = p;
    }
    __syncthreads();
    {
        float b0 = NEG_INF_F, b1 = NEG_INF_F;
#pragma unroll
        for (int q = 0; q < 4; ++q) {
            int2 p = mrg[t * 4 + q];
            int ks[2] = {p.x, p.y};
#pragma unroll
            for (int j = 0; j < 2; ++j) {
                float k = __int_as_float(ks[j]);
                float h = fmaxf(b0, k);
                float lo = fminf(b0, k);
                b0 = h;
                b1 = fmaxf(b1, lo);
            }
        }
        int rowG = rowBase + t;
        int* o = cand_row + (size_t)rowG * 16 + split * 2;
        o[0] = colBase + (__float_as_int(b0) & 0xFFF);
        o[1] = colBase + (__float_as_int(b1) & 0xFFF);
    }
}

// ------------------------------------------------------------------
// mergecol: per column, bf16-key top-6 of 192 block partials -> rows
// ------------------------------------------------------------------
__global__ __launch_bounds__(256) void mergecol_kernel(
    const unsigned* __restrict__ cand_col, int* __restrict__ col6)
{
    int col = blockIdx.x * 256 + threadIdx.x;   // 0..16383
    float bv0 = NEG_INF_F, bv1 = NEG_INF_F, bv2 = NEG_INF_F;
    float bv3 = NEG_INF_F, bv4 = NEG_INF_F, bv5 = NEG_INF_F;
    for (int s = 0; s < NCOLSLOT; ++s) {
        float k = __uint_as_float(cand_col[(size_t)s * NP + col]);
        float h;
        h = fmaxf(bv0, k); k = fminf(bv0, k); bv0 = h;
        h = fmaxf(bv1, k); k = fminf(bv1, k); bv1 = h;
        h = fmaxf(bv2, k); k = fminf(bv2, k); bv2 = h;
        h = fmaxf(bv3, k); k = fminf(bv3, k); bv3 = h;
        h = fmaxf(bv4, k); k = fminf(bv4, k); bv4 = h;
        bv5 = fmaxf(bv5, k);
    }
    const float thr = bv5;
    int r0 = 0, r1 = 0, r2 = 0, r3 = 0, r4 = 0, r5 = 0;
    int cnt = 0;
    for (int s = 0; s < NCOLSLOT; ++s) {
        unsigned ku = cand_col[(size_t)s * NP + col];
        float k = __uint_as_float(ku);
        bool take = (k >= thr) && (cnt < 6);
        int row = (s / 3) * 256 + (int)(ku & 0xFFu);
        r0 = (take && cnt == 0) ? row : r0;
        r1 = (take && cnt == 1) ? row : r1;
        r2 = (take && cnt == 2) ? row : r2;
        r3 = (take && cnt == 3) ? row : r3;
        r4 = (take && cnt == 4) ? row : r4;
        r5 = (take && cnt == 5) ? row : r5;
        cnt += take ? 1 : 0;
    }
    int* o = col6 + (size_t)col * 6;
    o[0] = r0; o[1] = r1; o[2] = r2; o[3] = r3; o[4] = r4; o[5] = r5;
}

// ------------------------------------------------------------------
// rescore_row: exact fp32 top-2 over 16 cands per row (wave per row)
// ------------------------------------------------------------------
__global__ __launch_bounds__(256) void rescore_row_kernel(
    const float* __restrict__ AT, const float* __restrict__ BT,
    const int* __restrict__ cand_row, float4* __restrict__ final12)
{
    const int t = threadIdx.x;
    const int w = t >> 6, l = t & 63;
    const int row = blockIdx.x * 4 + w;    // 0..16383
    float4 rv = *(const float4*)(AT + ((size_t)row << 8) + l * 4);
    float v0 = -4.f, v1 = -4.f; int i0 = 0x7fffffff, i1 = 0x7fffffff;
    const int* __restrict__ cl = cand_row + (size_t)row * 16;
#pragma unroll 4
    for (int j = 0; j < 16; ++j) {
        int idx = cl[j];
        float4 cv = *(const float4*)(BT + ((size_t)idx << 8) + l * 4);
        float d = rv.x * cv.x;
        d = fmaf(rv.y, cv.y, d);
        d = fmaf(rv.z, cv.z, d);
        d = fmaf(rv.w, cv.w, d);
#pragma unroll
        for (int m = 1; m < 64; m <<= 1) d += __shfl_xor(d, m, 64);
        if (d > v0 || (d == v0 && idx < i0)) {
            v1 = v0; i1 = i0; v0 = d; i0 = idx;
        } else if (d > v1 || (d == v1 && idx < i1)) {
            v1 = d; i1 = idx;
        }
    }
    if (l == 0) {
        float4 r; r.x = v0; r.y = v1;
        r.z = __int_as_float(i0); r.w = __int_as_float(i1);
        final12[row] = r;
    }
}

// ------------------------------------------------------------------
// rescore_col: exact fp32 top-2 over 6 cands per column (wave per col)
// ------------------------------------------------------------------
__global__ __launch_bounds__(256) void rescore_col_kernel(
    const float* __restrict__ AT, const float* __restrict__ BT,
    const int* __restrict__ col6,
    int* __restrict__ nn21, float* __restrict__ ratio21)
{
    const int t = threadIdx.x;
    const int w = t >> 6, l = t & 63;
    const int col = blockIdx.x * 4 + w;    // 0..16383
    float4 rv = *(const float4*)(BT + ((size_t)col << 8) + l * 4);
    float v0 = -4.f, v1 = -4.f; int i0 = 0x7fffffff, i1 = 0x7fffffff;
    const int* __restrict__ cl = col6 + (size_t)col * 6;
#pragma unroll
    for (int j = 0; j < 6; ++j) {
        int idx = cl[j];
        float4 cv = *(const float4*)(AT + ((size_t)idx << 8) + l * 4);
        float d = rv.x * cv.x;
        d = fmaf(rv.y, cv.y, d);
        d = fmaf(rv.z, cv.z, d);
        d = fmaf(rv.w, cv.w, d);
#pragma unroll
        for (int m = 1; m < 64; m <<= 1) d += __shfl_xor(d, m, 64);
        if (d > v0 || (d == v0 && idx < i0)) {
            v1 = v0; i1 = i0; v0 = d; i0 = idx;
        } else if (d > v1 || (d == v1 && idx < i1)) {
            v1 = d; i1 = idx;
        }
    }
    if (l == 0) {
        nn21[col] = i0;
        float d0 = sqrtf(fmaxf(2.f - 2.f * v0, 1e-12f));
        float d1 = sqrtf(fmaxf(2.f - 2.f * v1, 1e-12f));
        ratio21[col] = d0 / (d1 + EPSF);
    }
}

// ------------------------------------------------------------------
// final: mutual check, ratio test, border mask
// ------------------------------------------------------------------
__global__ void final_kernel(const float4* __restrict__ final12,
                             const int* __restrict__ nn21,
                             const float* __restrict__ ratio21,
                             float* __restrict__ out) {
    int i = blockIdx.x * blockDim.x + threadIdx.x;  // 0..16383
    float4 a = final12[i];
    float d0 = sqrtf(fmaxf(2.f - 2.f * a.x, 1e-12f));
    float d1 = sqrtf(fmaxf(2.f - 2.f * a.y, 1e-12f));
    int nn = __float_as_int(a.z);
    float r12 = d0 / (d1 + EPSF);
    bool mutual = (nn21[nn] == i);
    float r = fmaxf(r12, ratio21[nn]);
    int xA = i & (WDIM - 1), yA = i >> 7;
    int xB = nn & (WDIM - 1), yB = nn >> 7;
    bool border = (xA == 0) || (xA == WDIM - 1) || (yA == 0) || (yA == WDIM - 1) ||
                  (xB == 0) || (xB == WDIM - 1) || (yB == 0) || (yB == WDIM - 1);
    bool valid = mutual && (r < 0.95f) && !border;
    out[2 * i]       = valid ? d0 : 0.f;
    out[2 * i + 1]   = valid ? d1 : 0.f;
    out[2 * NP + i]  = (float)nn;
    out[3 * NP + i]  = valid ? 1.f : 0.f;
}

extern "C" void kernel_launch(void* const* d_in, const int* in_sizes, int n_in,
                              void* d_out, int out_size, void* d_ws, size_t ws_size,
                              hipStream_t stream) {
    (void)in_sizes; (void)n_in; (void)out_size; (void)ws_size;
    const float* A = (const float*)d_in[0];
    const float* B = (const float*)d_in[1];
    float* out = (float*)d_out;

    char* ws = (char*)d_ws;
    float* AT = (float*)ws;                                          // 16 MB
    float* BT = AT + (size_t)NP * CH;                                // 16 MB
    unsigned short* Abf = (unsigned short*)(BT + (size_t)NP * CH);   // 8 MB
    unsigned short* Bbf = Abf + (size_t)NP * CH;                     // 8 MB
    int* cand_row = (int*)(Bbf + (size_t)NP * CH);                   // 1 MB
    unsigned* cand_col = (unsigned*)(cand_row + (size_t)NP * 16);    // 12.6 MB
    int* col6 = (int*)(cand_col + (size_t)NCOLSLOT * NP);            // 0.4 MB
    float4* final12 = (float4*)(col6 + (size_t)NP * 6);              // 256 KB
    int* nn21 = (int*)(final12 + NP);                                // 64 KB
    float* ratio21 = (float*)(nn21 + NP);                            // 64 KB

    prep_kernel<<<512, 256, 0, stream>>>(A, B, AT, BT, Abf, Bbf);
    simk_kernel<<<NRT * SPLITS, 256, 0, stream>>>(Abf, Bbf, cand_row, cand_col);
    mergecol_kernel<<<NP / 256, 256, 0, stream>>>(cand_col, col6);
    rescore_row_kernel<<<NP / 4, 256, 0, stream>>>(AT, BT, cand_row, final12);
    rescore_col_kernel<<<NP / 4, 256, 0, stream>>>(AT, BT, col6, nn21, ratio21);
    final_kernel<<<NP / 256, 256, 0, stream>>>(final12, nn21, ratio21, out);
}

// Round 12
// 291.427 us; speedup vs baseline: 1.1455x; 1.0102x over previous
//
#include <hip/hip_runtime.h>
#include <math.h>

#define NP 16384      // pixels per map (128*128)
#define CH 256        // channels (K)
#define WDIM 128
#define EPSF 1e-8f

#define CHUNK 32
#define SPLITS 8
#define CPS (NP / SPLITS)            // 2048 cols per split
#define NCHUNK (CPS / CHUNK)         // 64
#define ROWS 256                     // rows per block (4 waves x 64)
#define NRT (NP / ROWS)              // 64 row tiles
#define CHUNK_BYTES (CHUNK * CH * 2) // 16384
#define NCOLSLOT (NRT * 3)           // 192 col-candidate slots per column
#define CBSTRIDE 262                 // colbuf row stride in floats

typedef short short8 __attribute__((ext_vector_type(8)));
typedef float floatx4 __attribute__((ext_vector_type(4)));

typedef __attribute__((address_space(1))) const unsigned int gu32;
typedef __attribute__((address_space(3))) unsigned int lu32;

#define NEG_INF_F __int_as_float(0xFF800000)
#define ROWKEY_MASK 0xFFFFF800u      // 21-bit sim | 11-bit local col

// ------------------------------------------------------------------
// prep: per-pixel 1/||d||, fp32 normalized transposed [pix][256],
// bf16 normalized swizzled (element ch stored at ch ^ ((pix&7)<<3))
// ------------------------------------------------------------------
__global__ __launch_bounds__(256) void prep_kernel(
    const float* __restrict__ A, const float* __restrict__ B,
    float* __restrict__ AT, float* __restrict__ BT,
    unsigned short* __restrict__ Abf, unsigned short* __restrict__ Bbf)
{
    __shared__ float tile[64 * 257];
    __shared__ float rnv[64];
    const int bid = blockIdx.x;
    const float* __restrict__ src = (bid < 256) ? A : B;
    float* __restrict__ dstT = (bid < 256) ? AT : BT;
    unsigned short* __restrict__ dstb = (bid < 256) ? Abf : Bbf;
    const int pixBase = (bid & 255) * 64;
    const int t = threadIdx.x;

    for (int k = 0; k < 64 * 256; k += 256) {
        int idx = k + t;
        int p = idx & 63;
        int c = idx >> 6;
        tile[p * 257 + c] = src[(size_t)c * NP + pixBase + p];
    }
    __syncthreads();
    if (t < 64) {
        float s = 0.f;
        for (int c = 0; c < 256; ++c) { float v = tile[t * 257 + c]; s = fmaf(v, v, s); }
        rnv[t] = 1.0f / sqrtf(s);
    }
    __syncthreads();
    for (int k = 0; k < 64 * 256; k += 256) {
        int idx = k + t;
        int p = idx >> 8;
        int c = idx & 255;
        dstT[((size_t)(pixBase + p) << 8) + c] = tile[p * 257 + c] * rnv[p];
    }
    for (int k = 0; k < 64 * 128; k += 256) {
        int idx = k + t;
        int p = idx >> 7;
        int c2 = (idx & 127) * 2;
        float rn = rnv[p];
        float v0 = tile[p * 257 + c2] * rn;
        float v1 = tile[p * 257 + c2 + 1] * rn;
        unsigned u0 = __float_as_uint(v0); u0 = (u0 + 0x7fffu + ((u0 >> 16) & 1u)) >> 16;
        unsigned u1 = __float_as_uint(v1); u1 = (u1 + 0x7fffu + ((u1 >> 16) & 1u)) >> 16;
        unsigned sw = ((unsigned)(p & 7)) << 3;
        int e = ((pixBase + p) << 8) + (c2 ^ (int)sw);
        *(unsigned*)(dstb + e) = (u0 & 0xffffu) | (u1 << 16);
    }
}

// ------------------------------------------------------------------
// simk ONE-PASS (R11 structure): per chunk both row running top-2
// (per lane, split by mi to halve dep chain; 21-bit keys) and col
// block top-3 (colbuf -> merge1 -> colbuf2 dbuf -> deferred merge2).
// Rows (A) = B-operand in regs (pinned); cols (B) staged in LDS.
// cand_row stores RAW packed keys (u32), 3 per split.
// ------------------------------------------------------------------
__global__ __launch_bounds__(256, 2) void simk_kernel(
    const unsigned short* __restrict__ Abf, const unsigned short* __restrict__ Bbf,
    unsigned* __restrict__ cand_row, unsigned* __restrict__ cand_col)
{
    __shared__ __align__(16) char smem[2 * CHUNK_BYTES];   // 32 KB staging
    __shared__ __align__(16) float colbuf[32 * CBSTRIDE];  // 33.5 KB
    __shared__ __align__(16) float2 colbuf2[2][32][9];     // 4.6 KB (dbuf)
    const int bid = blockIdx.x;
    const int rt = bid >> 3;
    const int split = bid & 7;
    const int t = threadIdx.x;
    const int w = t >> 6;
    const int l = t & 63;
    const int l15 = l & 15, lhi = l >> 4;
    const int rowBase = rt * ROWS;
    const int colBase = split * CPS;

    // --- row-descriptor fragments (B-operand) from A, pinned ---
    short8 Bfr[4][8];
#pragma unroll
    for (int ni = 0; ni < 4; ++ni) {
        int pix = rowBase + w * 64 + ni * 16 + l15;
        const unsigned short* pr = Abf + ((size_t)pix << 8);
        int sw = (pix & 7) << 3;
#pragma unroll
        for (int kk = 0; kk < 8; ++kk) {
            int ke = kk * 32 + lhi * 8;
            Bfr[ni][kk] = *(const short8*)(pr + (ke ^ sw));
        }
    }
#pragma unroll
    for (int ni = 0; ni < 4; ++ni)
#pragma unroll
        for (int kk = 0; kk < 8; ++kk)
            asm volatile("" : "+v"(Bfr[ni][kk]));

    // --- LDS byte offsets for A-operand frags (mi=0; mi=1 is +8192) ---
    int aoff[8];
    {
        int cp = l15;
        int sw = (cp & 7) << 3;
#pragma unroll
        for (int kk = 0; kk < 8; ++kk) {
            int ke = kk * 32 + lhi * 8;
            aoff[kk] = (cp * 256 + (ke ^ sw)) * 2;
        }
    }

    // row running top-2 per (mi, ni) stream — split by mi for ILP
    float tv0[2][4], tv1[2][4];
#pragma unroll
    for (int mi = 0; mi < 2; ++mi)
#pragma unroll
        for (int ni = 0; ni < 4; ++ni) { tv0[mi][ni] = NEG_INF_F; tv1[mi][ni] = NEG_INF_F; }

    const char* gbase = (const char*)(Bbf + ((size_t)colBase << 8));
    const floatx4 fzero = {0.f, 0.f, 0.f, 0.f};
    floatx4 acc[2][4];

#define STAGE(CIDX, BUFSEL) do {                                              \
        const char* gsrc_ = gbase + (size_t)(CIDX) * CHUNK_BYTES;             \
        char* bdst_ = smem + (BUFSEL) * CHUNK_BYTES;                          \
        _Pragma("unroll")                                                     \
        for (int r_ = 0; r_ < 4; ++r_) {                                      \
            int off_ = w * 4096 + r_ * 1024;                                  \
            __builtin_amdgcn_global_load_lds((gu32*)(gsrc_ + off_ + l * 16),  \
                                             (lu32*)(bdst_ + off_), 16, 0, 0);\
        }                                                                     \
    } while (0)

#define MERGE2(CIDX) do {                                                     \
        if (t < 32) {                                                         \
            float b0_ = NEG_INF_F, b1_ = NEG_INF_F, b2_ = NEG_INF_F;          \
            _Pragma("unroll")                                                 \
            for (int j_ = 0; j_ < 8; ++j_) {                                  \
                float2 v_ = colbuf2[(CIDX) & 1][t][j_];                       \
                float k_ = v_.x, h_;                                          \
                h_ = fmaxf(b0_, k_); k_ = fminf(b0_, k_); b0_ = h_;           \
                h_ = fmaxf(b1_, k_); k_ = fminf(b1_, k_); b1_ = h_;           \
                b2_ = fmaxf(b2_, k_);                                         \
                k_ = v_.y;                                                    \
                h_ = fmaxf(b0_, k_); k_ = fminf(b0_, k_); b0_ = h_;           \
                h_ = fmaxf(b1_, k_); k_ = fminf(b1_, k_); b1_ = h_;           \
                b2_ = fmaxf(b2_, k_);                                         \
            }                                                                 \
            int colG_ = colBase + (CIDX) * 32 + t;                            \
            cand_col[(size_t)(rt * 3 + 0) * NP + colG_] = __float_as_uint(b0_);\
            cand_col[(size_t)(rt * 3 + 1) * NP + colG_] = __float_as_uint(b1_);\
            cand_col[(size_t)(rt * 3 + 2) * NP + colG_] = __float_as_uint(b2_);\
        }                                                                     \
    } while (0)

    STAGE(0, 0);

    for (int c = 0; c < NCHUNK; ++c) {
        __syncthreads();   // B1: staging(c) ready; colbuf free; colbuf2[(c-1)&1] published
        if (c + 1 < NCHUNK) STAGE(c + 1, (c + 1) & 1);
        if (c > 0) MERGE2(c - 1);

        // ---- COMPUTE: 64 MFMA into acc ----
        {
            const char* buf = smem + (c & 1) * CHUNK_BYTES;
            __builtin_amdgcn_s_setprio(1);
            {
                short8 a0 = *(const short8*)(buf + aoff[0]);
                short8 a1 = *(const short8*)(buf + aoff[0] + 8192);
#pragma unroll
                for (int ni = 0; ni < 4; ++ni) {
                    acc[0][ni] = __builtin_amdgcn_mfma_f32_16x16x32_bf16(a0, Bfr[ni][0], fzero, 0, 0, 0);
                    acc[1][ni] = __builtin_amdgcn_mfma_f32_16x16x32_bf16(a1, Bfr[ni][0], fzero, 0, 0, 0);
                }
            }
#pragma unroll
            for (int kk = 1; kk < 8; ++kk) {
                short8 a0 = *(const short8*)(buf + aoff[kk]);
                short8 a1 = *(const short8*)(buf + aoff[kk] + 8192);
#pragma unroll
                for (int ni = 0; ni < 4; ++ni) {
                    acc[0][ni] = __builtin_amdgcn_mfma_f32_16x16x32_bf16(a0, Bfr[ni][kk], acc[0][ni], 0, 0, 0);
                    acc[1][ni] = __builtin_amdgcn_mfma_f32_16x16x32_bf16(a1, Bfr[ni][kk], acc[1][ni], 0, 0, 0);
                }
            }
            __builtin_amdgcn_s_setprio(0);
        }

        // ---- COL extract: per-lane sorted pair of 4 rows -> colbuf ----
        {
            const unsigned brb = ((unsigned)w << 6) | (unsigned)l15;
#pragma unroll
            for (int mi = 0; mi < 2; ++mi) {
#pragma unroll
                for (int reg = 0; reg < 4; ++reg) {
                    unsigned k0 = (__float_as_uint(acc[mi][0][reg]) & 0xFFFFFF00u) | brb;
                    unsigned k1 = (__float_as_uint(acc[mi][1][reg]) & 0xFFFFFF00u) | (brb | 16u);
                    unsigned k2 = (__float_as_uint(acc[mi][2][reg]) & 0xFFFFFF00u) | (brb | 32u);
                    unsigned k3 = (__float_as_uint(acc[mi][3][reg]) & 0xFFFFFF00u) | (brb | 48u);
                    float f0 = __uint_as_float(k0), f1 = __uint_as_float(k1);
                    float f2 = __uint_as_float(k2), f3 = __uint_as_float(k3);
                    float h01 = fmaxf(f0, f1), l01 = fminf(f0, f1);
                    float h23 = fmaxf(f2, f3), l23 = fminf(f2, f3);
                    float hi = fmaxf(h01, h23);
                    float lo = fmaxf(fminf(h01, h23), fmaxf(l01, l23));
                    int colL = mi * 16 + lhi * 4 + reg;
                    *(float2*)&colbuf[colL * CBSTRIDE + w * 32 + l15 * 2] = make_float2(hi, lo);
                }
            }
        }

        // ---- ROW top-2 (21-bit key | c*32 + col-local), mi-split chains ----
        {
            const int cS = c << 5;
#pragma unroll
            for (int mi = 0; mi < 2; ++mi) {
#pragma unroll
                for (int reg = 0; reg < 4; ++reg) {
                    const int ib = (lhi * 4 + mi * 16 + reg) | cS;
#pragma unroll
                    for (int ni = 0; ni < 4; ++ni) {
                        int kb = (__float_as_int(acc[mi][ni][reg]) & (int)ROWKEY_MASK) | ib;
                        float fk = __int_as_float(kb);
                        float h = fmaxf(tv0[mi][ni], fk);
                        float lo2 = fminf(tv0[mi][ni], fk);
                        tv0[mi][ni] = h;
                        tv1[mi][ni] = fmaxf(tv1[mi][ni], lo2);
                    }
                }
            }
        }

        __syncthreads();   // B2: colbuf complete
        // ---- merge1: 8 thr/col, interleaved slots (b64) -> colbuf2 ----
        {
            int col = t >> 3, g = t & 7;
            float a = NEG_INF_F, b = NEG_INF_F;
#pragma unroll
            for (int k = 0; k < 16; ++k) {
                float2 v = *(const float2*)&colbuf[col * CBSTRIDE + 2 * (g + (k << 3))];
                float t0 = fmaxf(a, v.x);
                float t1 = fmaxf(fminf(a, v.x), fmaxf(b, v.y));
                a = t0; b = t1;
            }
            colbuf2[c & 1][col][g] = make_float2(a, b);
        }
    }
    __syncthreads();       // publishes colbuf2[(NCHUNK-1)&1]; colbuf free
    MERGE2(NCHUNK - 1);
#undef STAGE
#undef MERGE2

    // ---- final row merge: 16 keys per row -> top-3 keys per split ----
    int4* mrg = (int4*)colbuf;     // [256 rows][4 lhi] int4
#pragma unroll
    for (int ni = 0; ni < 4; ++ni) {
        int rloc = w * 64 + ni * 16 + l15;
        int4 p;
        p.x = __float_as_int(tv0[0][ni]);
        p.y = __float_as_int(tv1[0][ni]);
        p.z = __float_as_int(tv0[1][ni]);
        p.w = __float_as_int(tv1[1][ni]);
        mrg[rloc * 4 + lhi] = p;
    }
    __syncthreads();
    {
        float b0 = NEG_INF_F, b1 = NEG_INF_F, b2 = NEG_INF_F;
#pragma unroll
        for (int q = 0; q < 4; ++q) {
            int4 p = mrg[t * 4 + q];
            int ks[4] = {p.x, p.y, p.z, p.w};
#pragma unroll
            for (int j = 0; j < 4; ++j) {
                float k = __int_as_float(ks[j]), h;
                h = fmaxf(b0, k); k = fminf(b0, k); b0 = h;
                h = fmaxf(b1, k); k = fminf(b1, k); b1 = h;
                b2 = fmaxf(b2, k);
            }
        }
        int rowG = rowBase + t;
        unsigned* o = cand_row + (size_t)rowG * 24 + split * 3;
        o[0] = __float_as_uint(b0);
        o[1] = __float_as_uint(b1);
        o[2] = __float_as_uint(b2);
    }
}

// ------------------------------------------------------------------
// mergecol: per column, bf16-key top-6 of 192 block partials -> rows
// ------------------------------------------------------------------
__global__ __launch_bounds__(256) void mergecol_kernel(
    const unsigned* __restrict__ cand_col, int* __restrict__ col6)
{
    int col = blockIdx.x * 256 + threadIdx.x;   // 0..16383
    float bv0 = NEG_INF_F, bv1 = NEG_INF_F, bv2 = NEG_INF_F;
    float bv3 = NEG_INF_F, bv4 = NEG_INF_F, bv5 = NEG_INF_F;
    for (int s = 0; s < NCOLSLOT; ++s) {
        float k = __uint_as_float(cand_col[(size_t)s * NP + col]);
        float h;
        h = fmaxf(bv0, k); k = fminf(bv0, k); bv0 = h;
        h = fmaxf(bv1, k); k = fminf(bv1, k); bv1 = h;
        h = fmaxf(bv2, k); k = fminf(bv2, k); bv2 = h;
        h = fmaxf(bv3, k); k = fminf(bv3, k); bv3 = h;
        h = fmaxf(bv4, k); k = fminf(bv4, k); bv4 = h;
        bv5 = fmaxf(bv5, k);
    }
    const float thr = bv5;
    int r0 = 0, r1 = 0, r2 = 0, r3 = 0, r4 = 0, r5 = 0;
    int cnt = 0;
    for (int s = 0; s < NCOLSLOT; ++s) {
        unsigned ku = cand_col[(size_t)s * NP + col];
        float k = __uint_as_float(ku);
        bool take = (k >= thr) && (cnt < 6);
        int row = (s / 3) * 256 + (int)(ku & 0xFFu);
        r0 = (take && cnt == 0) ? row : r0;
        r1 = (take && cnt == 1) ? row : r1;
        r2 = (take && cnt == 2) ? row : r2;
        r3 = (take && cnt == 3) ? row : r3;
        r4 = (take && cnt == 4) ? row : r4;
        r5 = (take && cnt == 5) ? row : r5;
        cnt += take ? 1 : 0;
    }
    int* o = col6 + (size_t)col * 6;
    o[0] = r0; o[1] = r1; o[2] = r2; o[3] = r3; o[4] = r4; o[5] = r5;
}

// ------------------------------------------------------------------
// rescore_row: key-threshold top-8 of 24, then exact fp32 top-2
// (wave per row; branch is wave-uniform)
// ------------------------------------------------------------------
__global__ __launch_bounds__(256) void rescore_row_kernel(
    const float* __restrict__ AT, const float* __restrict__ BT,
    const unsigned* __restrict__ cand_row, float4* __restrict__ final12)
{
    const int t = threadIdx.x;
    const int w = t >> 6, l = t & 63;
    const int row = blockIdx.x * 4 + w;    // 0..16383
    float4 rv = *(const float4*)(AT + ((size_t)row << 8) + l * 4);
    const unsigned* __restrict__ cl = cand_row + (size_t)row * 24;

    // 8th-largest key (all lanes compute identically from broadcast loads)
    float t8[8];
#pragma unroll
    for (int q = 0; q < 8; ++q) t8[q] = NEG_INF_F;
#pragma unroll
    for (int s = 0; s < 24; ++s) {
        float k = __uint_as_float(cl[s]);
#pragma unroll
        for (int q = 0; q < 8; ++q) {
            float h = fmaxf(t8[q], k);
            k = fminf(t8[q], k);
            t8[q] = h;
        }
    }
    const float thr = t8[7];

    float v0 = -4.f, v1 = -4.f; int i0 = 0x7fffffff, i1 = 0x7fffffff;
    int taken = 0;
    for (int s = 0; s < 24; ++s) {
        unsigned ku = cl[s];
        float kf = __uint_as_float(ku);
        if (kf >= thr && taken < 8) {      // wave-uniform
            ++taken;
            int idx = (s / 3) * CPS + (int)(ku & 0x7FFu);
            float4 cv = *(const float4*)(BT + ((size_t)idx << 8) + l * 4);
            float d = rv.x * cv.x;
            d = fmaf(rv.y, cv.y, d);
            d = fmaf(rv.z, cv.z, d);
            d = fmaf(rv.w, cv.w, d);
#pragma unroll
            for (int m = 1; m < 64; m <<= 1) d += __shfl_xor(d, m, 64);
            if (d > v0 || (d == v0 && idx < i0)) {
                v1 = v0; i1 = i0; v0 = d; i0 = idx;
            } else if (d > v1 || (d == v1 && idx < i1)) {
                v1 = d; i1 = idx;
            }
        }
    }
    if (l == 0) {
        float4 r; r.x = v0; r.y = v1;
        r.z = __int_as_float(i0); r.w = __int_as_float(i1);
        final12[row] = r;
    }
}

// ------------------------------------------------------------------
// rescore_col: exact fp32 top-2 over 6 cands per column (wave per col)
// ------------------------------------------------------------------
__global__ __launch_bounds__(256) void rescore_col_kernel(
    const float* __restrict__ AT, const float* __restrict__ BT,
    const int* __restrict__ col6,
    int* __restrict__ nn21, float* __restrict__ ratio21)
{
    const int t = threadIdx.x;
    const int w = t >> 6, l = t & 63;
    const int col = blockIdx.x * 4 + w;    // 0..16383
    float4 rv = *(const float4*)(BT + ((size_t)col << 8) + l * 4);
    float v0 = -4.f, v1 = -4.f; int i0 = 0x7fffffff, i1 = 0x7fffffff;
    const int* __restrict__ cl = col6 + (size_t)col * 6;
#pragma unroll
    for (int j = 0; j < 6; ++j) {
        int idx = cl[j];
        float4 cv = *(const float4*)(AT + ((size_t)idx << 8) + l * 4);
        float d = rv.x * cv.x;
        d = fmaf(rv.y, cv.y, d);
        d = fmaf(rv.z, cv.z, d);
        d = fmaf(rv.w, cv.w, d);
#pragma unroll
        for (int m = 1; m < 64; m <<= 1) d += __shfl_xor(d, m, 64);
        if (d > v0 || (d == v0 && idx < i0)) {
            v1 = v0; i1 = i0; v0 = d; i0 = idx;
        } else if (d > v1 || (d == v1 && idx < i1)) {
            v1 = d; i1 = idx;
        }
    }
    if (l == 0) {
        nn21[col] = i0;
        float d0 = sqrtf(fmaxf(2.f - 2.f * v0, 1e-12f));
        float d1 = sqrtf(fmaxf(2.f - 2.f * v1, 1e-12f));
        ratio21[col] = d0 / (d1 + EPSF);
    }
}

// ------------------------------------------------------------------
// final: mutual check, ratio test, border mask
// ------------------------------------------------------------------
__global__ void final_kernel(const float4* __restrict__ final12,
                             const int* __restrict__ nn21,
                             const float* __restrict__ ratio21,
                             float* __restrict__ out) {
    int i = blockIdx.x * blockDim.x + threadIdx.x;  // 0..16383
    float4 a = final12[i];
    float d0 = sqrtf(fmaxf(2.f - 2.f * a.x, 1e-12f));
    float d1 = sqrtf(fmaxf(2.f - 2.f * a.y, 1e-12f));
    int nn = __float_as_int(a.z);
    float r12 = d0 / (d1 + EPSF);
    bool mutual = (nn21[nn] == i);
    float r = fmaxf(r12, ratio21[nn]);
    int xA = i & (WDIM - 1), yA = i >> 7;
    int xB = nn & (WDIM - 1), yB = nn >> 7;
    bool border = (xA == 0) || (xA == WDIM - 1) || (yA == 0) || (yA == WDIM - 1) ||
                  (xB == 0) || (xB == WDIM - 1) || (yB == 0) || (yB == WDIM - 1);
    bool valid = mutual && (r < 0.95f) && !border;
    out[2 * i]       = valid ? d0 : 0.f;
    out[2 * i + 1]   = valid ? d1 : 0.f;
    out[2 * NP + i]  = (float)nn;
    out[3 * NP + i]  = valid ? 1.f : 0.f;
}

extern "C" void kernel_launch(void* const* d_in, const int* in_sizes, int n_in,
                              void* d_out, int out_size, void* d_ws, size_t ws_size,
                              hipStream_t stream) {
    (void)in_sizes; (void)n_in; (void)out_size; (void)ws_size;
    const float* A = (const float*)d_in[0];
    const float* B = (const float*)d_in[1];
    float* out = (float*)d_out;

    char* ws = (char*)d_ws;
    float* AT = (float*)ws;                                          // 16 MB
    float* BT = AT + (size_t)NP * CH;                                // 16 MB
    unsigned short* Abf = (unsigned short*)(BT + (size_t)NP * CH);   // 8 MB
    unsigned short* Bbf = Abf + (size_t)NP * CH;                     // 8 MB
    unsigned* cand_row = (unsigned*)(Bbf + (size_t)NP * CH);         // 1.5 MB
    unsigned* cand_col = cand_row + (size_t)NP * 24;                 // 12.6 MB
    int* col6 = (int*)(cand_col + (size_t)NCOLSLOT * NP);            // 0.4 MB
    float4* final12 = (float4*)(col6 + (size_t)NP * 6);              // 256 KB
    int* nn21 = (int*)(final12 + NP);                                // 64 KB
    float* ratio21 = (float*)(nn21 + NP);                            // 64 KB

    prep_kernel<<<512, 256, 0, stream>>>(A, B, AT, BT, Abf, Bbf);
    simk_kernel<<<NRT * SPLITS, 256, 0, stream>>>(Abf, Bbf, cand_row, cand_col);
    mergecol_kernel<<<NP / 256, 256, 0, stream>>>(cand_col, col6);
    rescore_row_kernel<<<NP / 4, 256, 0, stream>>>(AT, BT, cand_row, final12);
    rescore_col_kernel<<<NP / 4, 256, 0, stream>>>(AT, BT, col6, nn21, ratio21);
    final_kernel<<<NP / 256, 256, 0, stream>>>(final12, nn21, ratio21, out);
}

// Round 13
// 285.620 us; speedup vs baseline: 1.1688x; 1.0203x over previous
//
#include <hip/hip_runtime.h>
#include <math.h>

#define NP 16384      // pixels per map (128*128)
#define CH 256        // channels (K)
#define WDIM 128
#define EPSF 1e-8f

#define CHUNK 32
#define SPLITS 8
#define CPS (NP / SPLITS)            // 2048 cols per split
#define NCHUNK (CPS / CHUNK)         // 64
#define ROWS 256                     // rows per block (4 waves x 64)
#define NRT (NP / ROWS)              // 64 row tiles
#define CHUNK_BYTES (CHUNK * CH * 2) // 16384
#define NCOLSLOT (NRT * 3)           // 192 col-candidate slots per column
#define CBSTRIDE 262                 // colbuf row stride in floats

typedef short short8 __attribute__((ext_vector_type(8)));
typedef float floatx4 __attribute__((ext_vector_type(4)));

typedef __attribute__((address_space(1))) const unsigned int gu32;
typedef __attribute__((address_space(3))) unsigned int lu32;

#define NEG_INF_F __int_as_float(0xFF800000)
#define ROWKEY_MASK 0xFFFFF800u      // 21-bit sim | 11-bit local col

// ------------------------------------------------------------------
// prep: per-pixel 1/||d||, fp32 normalized transposed [pix][256],
// bf16 normalized swizzled (element ch stored at ch ^ ((pix&7)<<3))
// ------------------------------------------------------------------
__global__ __launch_bounds__(256) void prep_kernel(
    const float* __restrict__ A, const float* __restrict__ B,
    float* __restrict__ AT, float* __restrict__ BT,
    unsigned short* __restrict__ Abf, unsigned short* __restrict__ Bbf)
{
    __shared__ float tile[64 * 257];
    __shared__ float rnv[64];
    const int bid = blockIdx.x;
    const float* __restrict__ src = (bid < 256) ? A : B;
    float* __restrict__ dstT = (bid < 256) ? AT : BT;
    unsigned short* __restrict__ dstb = (bid < 256) ? Abf : Bbf;
    const int pixBase = (bid & 255) * 64;
    const int t = threadIdx.x;

    for (int k = 0; k < 64 * 256; k += 256) {
        int idx = k + t;
        int p = idx & 63;
        int c = idx >> 6;
        tile[p * 257 + c] = src[(size_t)c * NP + pixBase + p];
    }
    __syncthreads();
    if (t < 64) {
        float s = 0.f;
        for (int c = 0; c < 256; ++c) { float v = tile[t * 257 + c]; s = fmaf(v, v, s); }
        rnv[t] = 1.0f / sqrtf(s);
    }
    __syncthreads();
    for (int k = 0; k < 64 * 256; k += 256) {
        int idx = k + t;
        int p = idx >> 8;
        int c = idx & 255;
        dstT[((size_t)(pixBase + p) << 8) + c] = tile[p * 257 + c] * rnv[p];
    }
    for (int k = 0; k < 64 * 128; k += 256) {
        int idx = k + t;
        int p = idx >> 7;
        int c2 = (idx & 127) * 2;
        float rn = rnv[p];
        float v0 = tile[p * 257 + c2] * rn;
        float v1 = tile[p * 257 + c2 + 1] * rn;
        unsigned u0 = __float_as_uint(v0); u0 = (u0 + 0x7fffu + ((u0 >> 16) & 1u)) >> 16;
        unsigned u1 = __float_as_uint(v1); u1 = (u1 + 0x7fffu + ((u1 >> 16) & 1u)) >> 16;
        unsigned sw = ((unsigned)(p & 7)) << 3;
        int e = ((pixBase + p) << 8) + (c2 ^ (int)sw);
        *(unsigned*)(dstb + e) = (u0 & 0xffffu) | (u1 << 16);
    }
}

// ------------------------------------------------------------------
// simk ONE-PASS (R11 structure): per chunk both row running top-2
// (per lane, split by mi to halve dep chain; 21-bit keys) and col
// block top-3 (colbuf -> merge1 -> colbuf2 dbuf -> deferred merge2).
// Rows (A) = B-operand in regs (pinned); cols (B) staged in LDS.
// cand_row stores RAW packed keys (u32), 3 per split.
// R13 FIX: merge1 reads exactly the 64 float2 slots written per column
// (k < 8). R11/R12 read 128 slots (k < 16) -- half was stale LDS,
// corrupting the column top-3 (absmax 1.26). 4 waves write
// w*32 + l15*2 -> float2 slots 0..63 ONLY.
// ------------------------------------------------------------------
__global__ __launch_bounds__(256, 2) void simk_kernel(
    const unsigned short* __restrict__ Abf, const unsigned short* __restrict__ Bbf,
    unsigned* __restrict__ cand_row, unsigned* __restrict__ cand_col)
{
    __shared__ __align__(16) char smem[2 * CHUNK_BYTES];   // 32 KB staging
    __shared__ __align__(16) float colbuf[32 * CBSTRIDE];  // 33.5 KB
    __shared__ __align__(16) float2 colbuf2[2][32][9];     // 4.6 KB (dbuf)
    const int bid = blockIdx.x;
    const int rt = bid >> 3;
    const int split = bid & 7;
    const int t = threadIdx.x;
    const int w = t >> 6;
    const int l = t & 63;
    const int l15 = l & 15, lhi = l >> 4;
    const int rowBase = rt * ROWS;
    const int colBase = split * CPS;

    // --- row-descriptor fragments (B-operand) from A, pinned ---
    short8 Bfr[4][8];
#pragma unroll
    for (int ni = 0; ni < 4; ++ni) {
        int pix = rowBase + w * 64 + ni * 16 + l15;
        const unsigned short* pr = Abf + ((size_t)pix << 8);
        int sw = (pix & 7) << 3;
#pragma unroll
        for (int kk = 0; kk < 8; ++kk) {
            int ke = kk * 32 + lhi * 8;
            Bfr[ni][kk] = *(const short8*)(pr + (ke ^ sw));
        }
    }
#pragma unroll
    for (int ni = 0; ni < 4; ++ni)
#pragma unroll
        for (int kk = 0; kk < 8; ++kk)
            asm volatile("" : "+v"(Bfr[ni][kk]));

    // --- LDS byte offsets for A-operand frags (mi=0; mi=1 is +8192) ---
    int aoff[8];
    {
        int cp = l15;
        int sw = (cp & 7) << 3;
#pragma unroll
        for (int kk = 0; kk < 8; ++kk) {
            int ke = kk * 32 + lhi * 8;
            aoff[kk] = (cp * 256 + (ke ^ sw)) * 2;
        }
    }

    // row running top-2 per (mi, ni) stream — split by mi for ILP
    float tv0[2][4], tv1[2][4];
#pragma unroll
    for (int mi = 0; mi < 2; ++mi)
#pragma unroll
        for (int ni = 0; ni < 4; ++ni) { tv0[mi][ni] = NEG_INF_F; tv1[mi][ni] = NEG_INF_F; }

    const char* gbase = (const char*)(Bbf + ((size_t)colBase << 8));
    const floatx4 fzero = {0.f, 0.f, 0.f, 0.f};
    floatx4 acc[2][4];

#define STAGE(CIDX, BUFSEL) do {                                              \
        const char* gsrc_ = gbase + (size_t)(CIDX) * CHUNK_BYTES;             \
        char* bdst_ = smem + (BUFSEL) * CHUNK_BYTES;                          \
        _Pragma("unroll")                                                     \
        for (int r_ = 0; r_ < 4; ++r_) {                                      \
            int off_ = w * 4096 + r_ * 1024;                                  \
            __builtin_amdgcn_global_load_lds((gu32*)(gsrc_ + off_ + l * 16),  \
                                             (lu32*)(bdst_ + off_), 16, 0, 0);\
        }                                                                     \
    } while (0)

#define MERGE2(CIDX) do {                                                     \
        if (t < 32) {                                                         \
            float b0_ = NEG_INF_F, b1_ = NEG_INF_F, b2_ = NEG_INF_F;          \
            _Pragma("unroll")                                                 \
            for (int j_ = 0; j_ < 8; ++j_) {                                  \
                float2 v_ = colbuf2[(CIDX) & 1][t][j_];                       \
                float k_ = v_.x, h_;                                          \
                h_ = fmaxf(b0_, k_); k_ = fminf(b0_, k_); b0_ = h_;           \
                h_ = fmaxf(b1_, k_); k_ = fminf(b1_, k_); b1_ = h_;           \
                b2_ = fmaxf(b2_, k_);                                         \
                k_ = v_.y;                                                    \
                h_ = fmaxf(b0_, k_); k_ = fminf(b0_, k_); b0_ = h_;           \
                h_ = fmaxf(b1_, k_); k_ = fminf(b1_, k_); b1_ = h_;           \
                b2_ = fmaxf(b2_, k_);                                         \
            }                                                                 \
            int colG_ = colBase + (CIDX) * 32 + t;                            \
            cand_col[(size_t)(rt * 3 + 0) * NP + colG_] = __float_as_uint(b0_);\
            cand_col[(size_t)(rt * 3 + 1) * NP + colG_] = __float_as_uint(b1_);\
            cand_col[(size_t)(rt * 3 + 2) * NP + colG_] = __float_as_uint(b2_);\
        }                                                                     \
    } while (0)

    STAGE(0, 0);

    for (int c = 0; c < NCHUNK; ++c) {
        __syncthreads();   // B1: staging(c) ready; colbuf free; colbuf2[(c-1)&1] published
        if (c + 1 < NCHUNK) STAGE(c + 1, (c + 1) & 1);
        if (c > 0) MERGE2(c - 1);

        // ---- COMPUTE: 64 MFMA into acc ----
        {
            const char* buf = smem + (c & 1) * CHUNK_BYTES;
            __builtin_amdgcn_s_setprio(1);
            {
                short8 a0 = *(const short8*)(buf + aoff[0]);
                short8 a1 = *(const short8*)(buf + aoff[0] + 8192);
#pragma unroll
                for (int ni = 0; ni < 4; ++ni) {
                    acc[0][ni] = __builtin_amdgcn_mfma_f32_16x16x32_bf16(a0, Bfr[ni][0], fzero, 0, 0, 0);
                    acc[1][ni] = __builtin_amdgcn_mfma_f32_16x16x32_bf16(a1, Bfr[ni][0], fzero, 0, 0, 0);
                }
            }
#pragma unroll
            for (int kk = 1; kk < 8; ++kk) {
                short8 a0 = *(const short8*)(buf + aoff[kk]);
                short8 a1 = *(const short8*)(buf + aoff[kk] + 8192);
#pragma unroll
                for (int ni = 0; ni < 4; ++ni) {
                    acc[0][ni] = __builtin_amdgcn_mfma_f32_16x16x32_bf16(a0, Bfr[ni][kk], acc[0][ni], 0, 0, 0);
                    acc[1][ni] = __builtin_amdgcn_mfma_f32_16x16x32_bf16(a1, Bfr[ni][kk], acc[1][ni], 0, 0, 0);
                }
            }
            __builtin_amdgcn_s_setprio(0);
        }

        // ---- COL extract: per-lane sorted pair of 4 rows -> colbuf ----
        {
            const unsigned brb = ((unsigned)w << 6) | (unsigned)l15;
#pragma unroll
            for (int mi = 0; mi < 2; ++mi) {
#pragma unroll
                for (int reg = 0; reg < 4; ++reg) {
                    unsigned k0 = (__float_as_uint(acc[mi][0][reg]) & 0xFFFFFF00u) | brb;
                    unsigned k1 = (__float_as_uint(acc[mi][1][reg]) & 0xFFFFFF00u) | (brb | 16u);
                    unsigned k2 = (__float_as_uint(acc[mi][2][reg]) & 0xFFFFFF00u) | (brb | 32u);
                    unsigned k3 = (__float_as_uint(acc[mi][3][reg]) & 0xFFFFFF00u) | (brb | 48u);
                    float f0 = __uint_as_float(k0), f1 = __uint_as_float(k1);
                    float f2 = __uint_as_float(k2), f3 = __uint_as_float(k3);
                    float h01 = fmaxf(f0, f1), l01 = fminf(f0, f1);
                    float h23 = fmaxf(f2, f3), l23 = fminf(f2, f3);
                    float hi = fmaxf(h01, h23);
                    float lo = fmaxf(fminf(h01, h23), fmaxf(l01, l23));
                    int colL = mi * 16 + lhi * 4 + reg;
                    *(float2*)&colbuf[colL * CBSTRIDE + w * 32 + l15 * 2] = make_float2(hi, lo);
                }
            }
        }

        // ---- ROW top-2 (21-bit key | c*32 + col-local), mi-split chains ----
        {
            const int cS = c << 5;
#pragma unroll
            for (int mi = 0; mi < 2; ++mi) {
#pragma unroll
                for (int reg = 0; reg < 4; ++reg) {
                    const int ib = (lhi * 4 + mi * 16 + reg) | cS;
#pragma unroll
                    for (int ni = 0; ni < 4; ++ni) {
                        int kb = (__float_as_int(acc[mi][ni][reg]) & (int)ROWKEY_MASK) | ib;
                        float fk = __int_as_float(kb);
                        float h = fmaxf(tv0[mi][ni], fk);
                        float lo2 = fminf(tv0[mi][ni], fk);
                        tv0[mi][ni] = h;
                        tv1[mi][ni] = fmaxf(tv1[mi][ni], lo2);
                    }
                }
            }
        }

        __syncthreads();   // B2: colbuf complete
        // ---- merge1: 8 thr/col, interleaved slots s = g+8k, k<8 ----
        // (64 valid float2 slots per column; R11/R12 read k<16 = OOB)
        {
            int col = t >> 3, g = t & 7;
            float a = NEG_INF_F, b = NEG_INF_F;
#pragma unroll
            for (int k = 0; k < 8; ++k) {
                float2 v = *(const float2*)&colbuf[col * CBSTRIDE + 2 * (g + (k << 3))];
                float t0 = fmaxf(a, v.x);
                float t1 = fmaxf(fminf(a, v.x), fmaxf(b, v.y));
                a = t0; b = t1;
            }
            colbuf2[c & 1][col][g] = make_float2(a, b);
        }
    }
    __syncthreads();       // publishes colbuf2[(NCHUNK-1)&1]; colbuf free
    MERGE2(NCHUNK - 1);
#undef STAGE
#undef MERGE2

    // ---- final row merge: 16 keys per row -> top-3 keys per split ----
    int4* mrg = (int4*)colbuf;     // [256 rows][4 lhi] int4
#pragma unroll
    for (int ni = 0; ni < 4; ++ni) {
        int rloc = w * 64 + ni * 16 + l15;
        int4 p;
        p.x = __float_as_int(tv0[0][ni]);
        p.y = __float_as_int(tv1[0][ni]);
        p.z = __float_as_int(tv0[1][ni]);
        p.w = __float_as_int(tv1[1][ni]);
        mrg[rloc * 4 + lhi] = p;
    }
    __syncthreads();
    {
        float b0 = NEG_INF_F, b1 = NEG_INF_F, b2 = NEG_INF_F;
#pragma unroll
        for (int q = 0; q < 4; ++q) {
            int4 p = mrg[t * 4 + q];
            int ks[4] = {p.x, p.y, p.z, p.w};
#pragma unroll
            for (int j = 0; j < 4; ++j) {
                float k = __int_as_float(ks[j]), h;
                h = fmaxf(b0, k); k = fminf(b0, k); b0 = h;
                h = fmaxf(b1, k); k = fminf(b1, k); b1 = h;
                b2 = fmaxf(b2, k);
            }
        }
        int rowG = rowBase + t;
        unsigned* o = cand_row + (size_t)rowG * 24 + split * 3;
        o[0] = __float_as_uint(b0);
        o[1] = __float_as_uint(b1);
        o[2] = __float_as_uint(b2);
    }
}

// ------------------------------------------------------------------
// mergecol: per column, bf16-key top-6 of 192 block partials -> rows
// ------------------------------------------------------------------
__global__ __launch_bounds__(256) void mergecol_kernel(
    const unsigned* __restrict__ cand_col, int* __restrict__ col6)
{
    int col = blockIdx.x * 256 + threadIdx.x;   // 0..16383
    float bv0 = NEG_INF_F, bv1 = NEG_INF_F, bv2 = NEG_INF_F;
    float bv3 = NEG_INF_F, bv4 = NEG_INF_F, bv5 = NEG_INF_F;
    for (int s = 0; s < NCOLSLOT; ++s) {
        float k = __uint_as_float(cand_col[(size_t)s * NP + col]);
        float h;
        h = fmaxf(bv0, k); k = fminf(bv0, k); bv0 = h;
        h = fmaxf(bv1, k); k = fminf(bv1, k); bv1 = h;
        h = fmaxf(bv2, k); k = fminf(bv2, k); bv2 = h;
        h = fmaxf(bv3, k); k = fminf(bv3, k); bv3 = h;
        h = fmaxf(bv4, k); k = fminf(bv4, k); bv4 = h;
        bv5 = fmaxf(bv5, k);
    }
    const float thr = bv5;
    int r0 = 0, r1 = 0, r2 = 0, r3 = 0, r4 = 0, r5 = 0;
    int cnt = 0;
    for (int s = 0; s < NCOLSLOT; ++s) {
        unsigned ku = cand_col[(size_t)s * NP + col];
        float k = __uint_as_float(ku);
        bool take = (k >= thr) && (cnt < 6);
        int row = (s / 3) * 256 + (int)(ku & 0xFFu);
        r0 = (take && cnt == 0) ? row : r0;
        r1 = (take && cnt == 1) ? row : r1;
        r2 = (take && cnt == 2) ? row : r2;
        r3 = (take && cnt == 3) ? row : r3;
        r4 = (take && cnt == 4) ? row : r4;
        r5 = (take && cnt == 5) ? row : r5;
        cnt += take ? 1 : 0;
    }
    int* o = col6 + (size_t)col * 6;
    o[0] = r0; o[1] = r1; o[2] = r2; o[3] = r3; o[4] = r4; o[5] = r5;
}

// ------------------------------------------------------------------
// rescore_row: key-threshold top-8 of 24, then exact fp32 top-2
// (wave per row; branch is wave-uniform)
// ------------------------------------------------------------------
__global__ __launch_bounds__(256) void rescore_row_kernel(
    const float* __restrict__ AT, const float* __restrict__ BT,
    const unsigned* __restrict__ cand_row, float4* __restrict__ final12)
{
    const int t = threadIdx.x;
    const int w = t >> 6, l = t & 63;
    const int row = blockIdx.x * 4 + w;    // 0..16383
    float4 rv = *(const float4*)(AT + ((size_t)row << 8) + l * 4);
    const unsigned* __restrict__ cl = cand_row + (size_t)row * 24;

    // 8th-largest key (all lanes compute identically from broadcast loads)
    float t8[8];
#pragma unroll
    for (int q = 0; q < 8; ++q) t8[q] = NEG_INF_F;
#pragma unroll
    for (int s = 0; s < 24; ++s) {
        float k = __uint_as_float(cl[s]);
#pragma unroll
        for (int q = 0; q < 8; ++q) {
            float h = fmaxf(t8[q], k);
            k = fminf(t8[q], k);
            t8[q] = h;
        }
    }
    const float thr = t8[7];

    float v0 = -4.f, v1 = -4.f; int i0 = 0x7fffffff, i1 = 0x7fffffff;
    int taken = 0;
    for (int s = 0; s < 24; ++s) {
        unsigned ku = cl[s];
        float kf = __uint_as_float(ku);
        if (kf >= thr && taken < 8) {      // wave-uniform
            ++taken;
            int idx = (s / 3) * CPS + (int)(ku & 0x7FFu);
            float4 cv = *(const float4*)(BT + ((size_t)idx << 8) + l * 4);
            float d = rv.x * cv.x;
            d = fmaf(rv.y, cv.y, d);
            d = fmaf(rv.z, cv.z, d);
            d = fmaf(rv.w, cv.w, d);
#pragma unroll
            for (int m = 1; m < 64; m <<= 1) d += __shfl_xor(d, m, 64);
            if (d > v0 || (d == v0 && idx < i0)) {
                v1 = v0; i1 = i0; v0 = d; i0 = idx;
            } else if (d > v1 || (d == v1 && idx < i1)) {
                v1 = d; i1 = idx;
            }
        }
    }
    if (l == 0) {
        float4 r; r.x = v0; r.y = v1;
        r.z = __int_as_float(i0); r.w = __int_as_float(i1);
        final12[row] = r;
    }
}

// ------------------------------------------------------------------
// rescore_col: exact fp32 top-2 over 6 cands per column (wave per col)
// ------------------------------------------------------------------
__global__ __launch_bounds__(256) void rescore_col_kernel(
    const float* __restrict__ AT, const float* __restrict__ BT,
    const int* __restrict__ col6,
    int* __restrict__ nn21, float* __restrict__ ratio21)
{
    const int t = threadIdx.x;
    const int w = t >> 6, l = t & 63;
    const int col = blockIdx.x * 4 + w;    // 0..16383
    float4 rv = *(const float4*)(BT + ((size_t)col << 8) + l * 4);
    float v0 = -4.f, v1 = -4.f; int i0 = 0x7fffffff, i1 = 0x7fffffff;
    const int* __restrict__ cl = col6 + (size_t)col * 6;
#pragma unroll
    for (int j = 0; j < 6; ++j) {
        int idx = cl[j];
        float4 cv = *(const float4*)(AT + ((size_t)idx << 8) + l * 4);
        float d = rv.x * cv.x;
        d = fmaf(rv.y, cv.y, d);
        d = fmaf(rv.z, cv.z, d);
        d = fmaf(rv.w, cv.w, d);
#pragma unroll
        for (int m = 1; m < 64; m <<= 1) d += __shfl_xor(d, m, 64);
        if (d > v0 || (d == v0 && idx < i0)) {
            v1 = v0; i1 = i0; v0 = d; i0 = idx;
        } else if (d > v1 || (d == v1 && idx < i1)) {
            v1 = d; i1 = idx;
        }
    }
    if (l == 0) {
        nn21[col] = i0;
        float d0 = sqrtf(fmaxf(2.f - 2.f * v0, 1e-12f));
        float d1 = sqrtf(fmaxf(2.f - 2.f * v1, 1e-12f));
        ratio21[col] = d0 / (d1 + EPSF);
    }
}

// ------------------------------------------------------------------
// final: mutual check, ratio test, border mask
// ------------------------------------------------------------------
__global__ void final_kernel(const float4* __restrict__ final12,
                             const int* __restrict__ nn21,
                             const float* __restrict__ ratio21,
                             float* __restrict__ out) {
    int i = blockIdx.x * blockDim.x + threadIdx.x;  // 0..16383
    float4 a = final12[i];
    float d0 = sqrtf(fmaxf(2.f - 2.f * a.x, 1e-12f));
    float d1 = sqrtf(fmaxf(2.f - 2.f * a.y, 1e-12f));
    int nn = __float_as_int(a.z);
    float r12 = d0 / (d1 + EPSF);
    bool mutual = (nn21[nn] == i);
    float r = fmaxf(r12, ratio21[nn]);
    int xA = i & (WDIM - 1), yA = i >> 7;
    int xB = nn & (WDIM - 1), yB = nn >> 7;
    bool border = (xA == 0) || (xA == WDIM - 1) || (yA == 0) || (yA == WDIM - 1) ||
                  (xB == 0) || (xB == WDIM - 1) || (yB == 0) || (yB == WDIM - 1);
    bool valid = mutual && (r < 0.95f) && !border;
    out[2 * i]       = valid ? d0 : 0.f;
    out[2 * i + 1]   = valid ? d1 : 0.f;
    out[2 * NP + i]  = (float)nn;
    out[3 * NP + i]  = valid ? 1.f : 0.f;
}

extern "C" void kernel_launch(void* const* d_in, const int* in_sizes, int n_in,
                              void* d_out, int out_size, void* d_ws, size_t ws_size,
                              hipStream_t stream) {
    (void)in_sizes; (void)n_in; (void)out_size; (void)ws_size;
    const float* A = (const float*)d_in[0];
    const float* B = (const float*)d_in[1];
    float* out = (float*)d_out;

    char* ws = (char*)d_ws;
    float* AT = (float*)ws;                                          // 16 MB
    float* BT = AT + (size_t)NP * CH;                                // 16 MB
    unsigned short* Abf = (unsigned short*)(BT + (size_t)NP * CH);   // 8 MB
    unsigned short* Bbf = Abf + (size_t)NP * CH;                     // 8 MB
    unsigned* cand_row = (unsigned*)(Bbf + (size_t)NP * CH);         // 1.5 MB
    unsigned* cand_col = cand_row + (size_t)NP * 24;                 // 12.6 MB
    int* col6 = (int*)(cand_col + (size_t)NCOLSLOT * NP);            // 0.4 MB
    float4* final12 = (float4*)(col6 + (size_t)NP * 6);              // 256 KB
    int* nn21 = (int*)(final12 + NP);                                // 64 KB
    float* ratio21 = (float*)(nn21 + NP);                            // 64 KB

    prep_kernel<<<512, 256, 0, stream>>>(A, B, AT, BT, Abf, Bbf);
    simk_kernel<<<NRT * SPLITS, 256, 0, stream>>>(Abf, Bbf, cand_row, cand_col);
    mergecol_kernel<<<NP / 256, 256, 0, stream>>>(cand_col, col6);
    rescore_row_kernel<<<NP / 4, 256, 0, stream>>>(AT, BT, cand_row, final12);
    rescore_col_kernel<<<NP / 4, 256, 0, stream>>>(AT, BT, col6, nn21, ratio21);
    final_kernel<<<NP / 256, 256, 0, stream>>>(final12, nn21, ratio21, out);
}

// Round 14
// 280.008 us; speedup vs baseline: 1.1922x; 1.0200x over previous
//
#include <hip/hip_runtime.h>
#include <math.h>

#define NP 16384      // pixels per map (128*128)
#define CH 256        // channels (K)
#define WDIM 128
#define EPSF 1e-8f

#define CHUNK 32
#define SPLITS 8
#define CPS (NP / SPLITS)            // 2048 cols per split
#define NCHUNK (CPS / CHUNK)         // 64
#define ROWS 256                     // rows per block (4 waves x 64)
#define NRT (NP / ROWS)              // 64 row tiles
#define CHUNK_BYTES (CHUNK * CH * 2) // 16384
#define NCOLSLOT (NRT * 3)           // 192 col-candidate slots per column

typedef short short8 __attribute__((ext_vector_type(8)));
typedef float floatx4 __attribute__((ext_vector_type(4)));

typedef __attribute__((address_space(1))) const unsigned int gu32;
typedef __attribute__((address_space(3))) unsigned int lu32;

#define NEG_INF_F __int_as_float(0xFF800000)
#define ROWKEY_MASK 0xFFFFF800u      // 21-bit sim | 11-bit local col

// ------------------------------------------------------------------
// prep: per-pixel 1/||d||, fp32 normalized transposed [pix][256],
// bf16 normalized swizzled (element ch stored at ch ^ ((pix&7)<<3))
// ------------------------------------------------------------------
__global__ __launch_bounds__(256) void prep_kernel(
    const float* __restrict__ A, const float* __restrict__ B,
    float* __restrict__ AT, float* __restrict__ BT,
    unsigned short* __restrict__ Abf, unsigned short* __restrict__ Bbf)
{
    __shared__ float tile[64 * 257];
    __shared__ float rnv[64];
    const int bid = blockIdx.x;
    const float* __restrict__ src = (bid < 256) ? A : B;
    float* __restrict__ dstT = (bid < 256) ? AT : BT;
    unsigned short* __restrict__ dstb = (bid < 256) ? Abf : Bbf;
    const int pixBase = (bid & 255) * 64;
    const int t = threadIdx.x;

    for (int k = 0; k < 64 * 256; k += 256) {
        int idx = k + t;
        int p = idx & 63;
        int c = idx >> 6;
        tile[p * 257 + c] = src[(size_t)c * NP + pixBase + p];
    }
    __syncthreads();
    if (t < 64) {
        float s = 0.f;
        for (int c = 0; c < 256; ++c) { float v = tile[t * 257 + c]; s = fmaf(v, v, s); }
        rnv[t] = 1.0f / sqrtf(s);
    }
    __syncthreads();
    for (int k = 0; k < 64 * 256; k += 256) {
        int idx = k + t;
        int p = idx >> 8;
        int c = idx & 255;
        dstT[((size_t)(pixBase + p) << 8) + c] = tile[p * 257 + c] * rnv[p];
    }
    for (int k = 0; k < 64 * 128; k += 256) {
        int idx = k + t;
        int p = idx >> 7;
        int c2 = (idx & 127) * 2;
        float rn = rnv[p];
        float v0 = tile[p * 257 + c2] * rn;
        float v1 = tile[p * 257 + c2 + 1] * rn;
        unsigned u0 = __float_as_uint(v0); u0 = (u0 + 0x7fffu + ((u0 >> 16) & 1u)) >> 16;
        unsigned u1 = __float_as_uint(v1); u1 = (u1 + 0x7fffu + ((u1 >> 16) & 1u)) >> 16;
        unsigned sw = ((unsigned)(p & 7)) << 3;
        int e = ((pixBase + p) << 8) + (c2 ^ (int)sw);
        *(unsigned*)(dstb + e) = (u0 & 0xffffu) | (u1 << 16);
    }
}

// ------------------------------------------------------------------
// simk ONE-PASS, ONE barrier per chunk:
// col path uses WAVE-PRIVATE LDS (cbw[w]) — same-wave DS ops are
// in-order, so write-pairs -> read-back needs no __syncthreads.
// Per chunk: STAGE(c+1) | MERGE2(c-1) | 64 MFMA | col extract (8
// sorted pairs -> cbw) | row top-2 | wave merge (2 lanes/col, top-2
// of 16 pairs) -> colwave dbuf. MERGE2 (t<32): top-3 of 8 partials
// per col -> global cand_col (deferred one chunk).
// Rows (A) = B-operand in regs (pinned). cand_row = raw 21|11 keys.
// ------------------------------------------------------------------
__global__ __launch_bounds__(256, 2) void simk_kernel(
    const unsigned short* __restrict__ Abf, const unsigned short* __restrict__ Bbf,
    unsigned* __restrict__ cand_row, unsigned* __restrict__ cand_col)
{
    __shared__ __align__(16) char smem[2 * CHUNK_BYTES];      // 32 KB staging
    __shared__ __align__(16) float2 cbw[4][32 * 17 + 4];      // 17.5 KB wave-private
    __shared__ __align__(16) float2 colwave[2][32][9];        // 4.6 KB dbuf
    const int bid = blockIdx.x;
    const int rt = bid >> 3;
    const int split = bid & 7;
    const int t = threadIdx.x;
    const int w = t >> 6;
    const int l = t & 63;
    const int l15 = l & 15, lhi = l >> 4;
    const int rowBase = rt * ROWS;
    const int colBase = split * CPS;

    // --- row-descriptor fragments (B-operand) from A, pinned ---
    short8 Bfr[4][8];
#pragma unroll
    for (int ni = 0; ni < 4; ++ni) {
        int pix = rowBase + w * 64 + ni * 16 + l15;
        const unsigned short* pr = Abf + ((size_t)pix << 8);
        int sw = (pix & 7) << 3;
#pragma unroll
        for (int kk = 0; kk < 8; ++kk) {
            int ke = kk * 32 + lhi * 8;
            Bfr[ni][kk] = *(const short8*)(pr + (ke ^ sw));
        }
    }
#pragma unroll
    for (int ni = 0; ni < 4; ++ni)
#pragma unroll
        for (int kk = 0; kk < 8; ++kk)
            asm volatile("" : "+v"(Bfr[ni][kk]));

    // --- LDS byte offsets for A-operand frags (mi=0; mi=1 is +8192) ---
    int aoff[8];
    {
        int cp = l15;
        int sw = (cp & 7) << 3;
#pragma unroll
        for (int kk = 0; kk < 8; ++kk) {
            int ke = kk * 32 + lhi * 8;
            aoff[kk] = (cp * 256 + (ke ^ sw)) * 2;
        }
    }

    // row running top-2 per (mi, ni) stream — split by mi for ILP
    float tv0[2][4], tv1[2][4];
#pragma unroll
    for (int mi = 0; mi < 2; ++mi)
#pragma unroll
        for (int ni = 0; ni < 4; ++ni) { tv0[mi][ni] = NEG_INF_F; tv1[mi][ni] = NEG_INF_F; }

    const char* gbase = (const char*)(Bbf + ((size_t)colBase << 8));
    const floatx4 fzero = {0.f, 0.f, 0.f, 0.f};
    floatx4 acc[2][4];

#define STAGE(CIDX, BUFSEL) do {                                              \
        const char* gsrc_ = gbase + (size_t)(CIDX) * CHUNK_BYTES;             \
        char* bdst_ = smem + (BUFSEL) * CHUNK_BYTES;                          \
        _Pragma("unroll")                                                     \
        for (int r_ = 0; r_ < 4; ++r_) {                                      \
            int off_ = w * 4096 + r_ * 1024;                                  \
            __builtin_amdgcn_global_load_lds((gu32*)(gsrc_ + off_ + l * 16),  \
                                             (lu32*)(bdst_ + off_), 16, 0, 0);\
        }                                                                     \
    } while (0)

#define MERGE2(CIDX) do {                                                     \
        if (t < 32) {                                                         \
            float b0_ = NEG_INF_F, b1_ = NEG_INF_F, b2_ = NEG_INF_F;          \
            _Pragma("unroll")                                                 \
            for (int j_ = 0; j_ < 8; ++j_) {                                  \
                float2 v_ = colwave[(CIDX) & 1][t][j_];                       \
                float k_ = v_.x, h_;                                          \
                h_ = fmaxf(b0_, k_); k_ = fminf(b0_, k_); b0_ = h_;           \
                h_ = fmaxf(b1_, k_); k_ = fminf(b1_, k_); b1_ = h_;           \
                b2_ = fmaxf(b2_, k_);                                         \
                k_ = v_.y;                                                    \
                h_ = fmaxf(b0_, k_); k_ = fminf(b0_, k_); b0_ = h_;           \
                h_ = fmaxf(b1_, k_); k_ = fminf(b1_, k_); b1_ = h_;           \
                b2_ = fmaxf(b2_, k_);                                         \
            }                                                                 \
            int colG_ = colBase + (CIDX) * 32 + t;                            \
            cand_col[(size_t)(rt * 3 + 0) * NP + colG_] = __float_as_uint(b0_);\
            cand_col[(size_t)(rt * 3 + 1) * NP + colG_] = __float_as_uint(b1_);\
            cand_col[(size_t)(rt * 3 + 2) * NP + colG_] = __float_as_uint(b2_);\
        }                                                                     \
    } while (0)

    STAGE(0, 0);

    for (int c = 0; c < NCHUNK; ++c) {
        __syncthreads();   // B1: staging(c) ready; colwave[(c-1)&1] published
        if (c + 1 < NCHUNK) STAGE(c + 1, (c + 1) & 1);
        if (c > 0) MERGE2(c - 1);

        // ---- COMPUTE: 64 MFMA into acc ----
        {
            const char* buf = smem + (c & 1) * CHUNK_BYTES;
            __builtin_amdgcn_s_setprio(1);
            {
                short8 a0 = *(const short8*)(buf + aoff[0]);
                short8 a1 = *(const short8*)(buf + aoff[0] + 8192);
#pragma unroll
                for (int ni = 0; ni < 4; ++ni) {
                    acc[0][ni] = __builtin_amdgcn_mfma_f32_16x16x32_bf16(a0, Bfr[ni][0], fzero, 0, 0, 0);
                    acc[1][ni] = __builtin_amdgcn_mfma_f32_16x16x32_bf16(a1, Bfr[ni][0], fzero, 0, 0, 0);
                }
            }
#pragma unroll
            for (int kk = 1; kk < 8; ++kk) {
                short8 a0 = *(const short8*)(buf + aoff[kk]);
                short8 a1 = *(const short8*)(buf + aoff[kk] + 8192);
#pragma unroll
                for (int ni = 0; ni < 4; ++ni) {
                    acc[0][ni] = __builtin_amdgcn_mfma_f32_16x16x32_bf16(a0, Bfr[ni][kk], acc[0][ni], 0, 0, 0);
                    acc[1][ni] = __builtin_amdgcn_mfma_f32_16x16x32_bf16(a1, Bfr[ni][kk], acc[1][ni], 0, 0, 0);
                }
            }
            __builtin_amdgcn_s_setprio(0);
        }

        // ---- COL extract: per-lane sorted pair of 4 rows -> cbw[w] ----
        // (wave-private; slot = col*17 + l15; conflict-free writes)
        {
            const unsigned brb = ((unsigned)w << 6) | (unsigned)l15;
#pragma unroll
            for (int mi = 0; mi < 2; ++mi) {
#pragma unroll
                for (int reg = 0; reg < 4; ++reg) {
                    unsigned k0 = (__float_as_uint(acc[mi][0][reg]) & 0xFFFFFF00u) | brb;
                    unsigned k1 = (__float_as_uint(acc[mi][1][reg]) & 0xFFFFFF00u) | (brb | 16u);
                    unsigned k2 = (__float_as_uint(acc[mi][2][reg]) & 0xFFFFFF00u) | (brb | 32u);
                    unsigned k3 = (__float_as_uint(acc[mi][3][reg]) & 0xFFFFFF00u) | (brb | 48u);
                    float f0 = __uint_as_float(k0), f1 = __uint_as_float(k1);
                    float f2 = __uint_as_float(k2), f3 = __uint_as_float(k3);
                    float h01 = fmaxf(f0, f1), l01 = fminf(f0, f1);
                    float h23 = fmaxf(f2, f3), l23 = fminf(f2, f3);
                    float hi = fmaxf(h01, h23);
                    float lo = fmaxf(fminf(h01, h23), fmaxf(l01, l23));
                    int colL = mi * 16 + lhi * 4 + reg;
                    cbw[w][colL * 17 + l15] = make_float2(hi, lo);
                }
            }
        }

        // ---- ROW top-2 (21-bit key | c*32 + col-local), mi-split chains ----
        {
            const int cS = c << 5;
#pragma unroll
            for (int mi = 0; mi < 2; ++mi) {
#pragma unroll
                for (int reg = 0; reg < 4; ++reg) {
                    const int ib = (lhi * 4 + mi * 16 + reg) | cS;
#pragma unroll
                    for (int ni = 0; ni < 4; ++ni) {
                        int kb = (__float_as_int(acc[mi][ni][reg]) & (int)ROWKEY_MASK) | ib;
                        float fk = __int_as_float(kb);
                        float h = fmaxf(tv0[mi][ni], fk);
                        float lo2 = fminf(tv0[mi][ni], fk);
                        tv0[mi][ni] = h;
                        tv1[mi][ni] = fmaxf(tv1[mi][ni], lo2);
                    }
                }
            }
        }

        // ---- wave merge (no barrier: same-wave DS ops are in-order):
        //      2 lanes/col read 8 pairs each -> top-2 of 16 -> colwave ----
        {
            int colR = l >> 1, half = l & 1;
            const float2* src = &cbw[w][colR * 17 + half * 8];
            float a = NEG_INF_F, b = NEG_INF_F;
#pragma unroll
            for (int j = 0; j < 8; ++j) {
                float2 v = src[j];
                float t0 = fmaxf(a, v.x);
                float t1 = fmaxf(fminf(a, v.x), fmaxf(b, v.y));
                a = t0; b = t1;
            }
            colwave[c & 1][colR][w * 2 + half] = make_float2(a, b);
        }
    }
    __syncthreads();       // publishes colwave[(NCHUNK-1)&1]; cbw free
    MERGE2(NCHUNK - 1);
#undef STAGE
#undef MERGE2

    // ---- final row merge: 16 keys per row -> top-3 keys per split ----
    int4* mrg = (int4*)cbw;        // [256 rows][4 lhi] int4 = 16 KB (cbw is 17.5)
#pragma unroll
    for (int ni = 0; ni < 4; ++ni) {
        int rloc = w * 64 + ni * 16 + l15;
        int4 p;
        p.x = __float_as_int(tv0[0][ni]);
        p.y = __float_as_int(tv1[0][ni]);
        p.z = __float_as_int(tv0[1][ni]);
        p.w = __float_as_int(tv1[1][ni]);
        mrg[rloc * 4 + lhi] = p;
    }
    __syncthreads();
    {
        float b0 = NEG_INF_F, b1 = NEG_INF_F, b2 = NEG_INF_F;
#pragma unroll
        for (int q = 0; q < 4; ++q) {
            int4 p = mrg[t * 4 + q];
            int ks[4] = {p.x, p.y, p.z, p.w};
#pragma unroll
            for (int j = 0; j < 4; ++j) {
                float k = __int_as_float(ks[j]), h;
                h = fmaxf(b0, k); k = fminf(b0, k); b0 = h;
                h = fmaxf(b1, k); k = fminf(b1, k); b1 = h;
                b2 = fmaxf(b2, k);
            }
        }
        int rowG = rowBase + t;
        unsigned* o = cand_row + (size_t)rowG * 24 + split * 3;
        o[0] = __float_as_uint(b0);
        o[1] = __float_as_uint(b1);
        o[2] = __float_as_uint(b2);
    }
}

// ------------------------------------------------------------------
// mergecol: per column, bf16-key top-6 of 192 block partials -> rows
// ------------------------------------------------------------------
__global__ __launch_bounds__(256) void mergecol_kernel(
    const unsigned* __restrict__ cand_col, int* __restrict__ col6)
{
    int col = blockIdx.x * 256 + threadIdx.x;   // 0..16383
    float bv0 = NEG_INF_F, bv1 = NEG_INF_F, bv2 = NEG_INF_F;
    float bv3 = NEG_INF_F, bv4 = NEG_INF_F, bv5 = NEG_INF_F;
    for (int s = 0; s < NCOLSLOT; ++s) {
        float k = __uint_as_float(cand_col[(size_t)s * NP + col]);
        float h;
        h = fmaxf(bv0, k); k = fminf(bv0, k); bv0 = h;
        h = fmaxf(bv1, k); k = fminf(bv1, k); bv1 = h;
        h = fmaxf(bv2, k); k = fminf(bv2, k); bv2 = h;
        h = fmaxf(bv3, k); k = fminf(bv3, k); bv3 = h;
        h = fmaxf(bv4, k); k = fminf(bv4, k); bv4 = h;
        bv5 = fmaxf(bv5, k);
    }
    const float thr = bv5;
    int r0 = 0, r1 = 0, r2 = 0, r3 = 0, r4 = 0, r5 = 0;
    int cnt = 0;
    for (int s = 0; s < NCOLSLOT; ++s) {
        unsigned ku = cand_col[(size_t)s * NP + col];
        float k = __uint_as_float(ku);
        bool take = (k >= thr) && (cnt < 6);
        int row = (s / 3) * 256 + (int)(ku & 0xFFu);
        r0 = (take && cnt == 0) ? row : r0;
        r1 = (take && cnt == 1) ? row : r1;
        r2 = (take && cnt == 2) ? row : r2;
        r3 = (take && cnt == 3) ? row : r3;
        r4 = (take && cnt == 4) ? row : r4;
        r5 = (take && cnt == 5) ? row : r5;
        cnt += take ? 1 : 0;
    }
    int* o = col6 + (size_t)col * 6;
    o[0] = r0; o[1] = r1; o[2] = r2; o[3] = r3; o[4] = r4; o[5] = r5;
}

// ------------------------------------------------------------------
// rescore_row: key-threshold top-8 of 24, then exact fp32 top-2
// (wave per row; branch is wave-uniform)
// ------------------------------------------------------------------
__global__ __launch_bounds__(256) void rescore_row_kernel(
    const float* __restrict__ AT, const float* __restrict__ BT,
    const unsigned* __restrict__ cand_row, float4* __restrict__ final12)
{
    const int t = threadIdx.x;
    const int w = t >> 6, l = t & 63;
    const int row = blockIdx.x * 4 + w;    // 0..16383
    float4 rv = *(const float4*)(AT + ((size_t)row << 8) + l * 4);
    const unsigned* __restrict__ cl = cand_row + (size_t)row * 24;

    // 8th-largest key (all lanes compute identically from broadcast loads)
    float t8[8];
#pragma unroll
    for (int q = 0; q < 8; ++q) t8[q] = NEG_INF_F;
#pragma unroll
    for (int s = 0; s < 24; ++s) {
        float k = __uint_as_float(cl[s]);
#pragma unroll
        for (int q = 0; q < 8; ++q) {
            float h = fmaxf(t8[q], k);
            k = fminf(t8[q], k);
            t8[q] = h;
        }
    }
    const float thr = t8[7];

    float v0 = -4.f, v1 = -4.f; int i0 = 0x7fffffff, i1 = 0x7fffffff;
    int taken = 0;
    for (int s = 0; s < 24; ++s) {
        unsigned ku = cl[s];
        float kf = __uint_as_float(ku);
        if (kf >= thr && taken < 8) {      // wave-uniform
            ++taken;
            int idx = (s / 3) * CPS + (int)(ku & 0x7FFu);
            float4 cv = *(const float4*)(BT + ((size_t)idx << 8) + l * 4);
            float d = rv.x * cv.x;
            d = fmaf(rv.y, cv.y, d);
            d = fmaf(rv.z, cv.z, d);
            d = fmaf(rv.w, cv.w, d);
#pragma unroll
            for (int m = 1; m < 64; m <<= 1) d += __shfl_xor(d, m, 64);
            if (d > v0 || (d == v0 && idx < i0)) {
                v1 = v0; i1 = i0; v0 = d; i0 = idx;
            } else if (d > v1 || (d == v1 && idx < i1)) {
                v1 = d; i1 = idx;
            }
        }
    }
    if (l == 0) {
        float4 r; r.x = v0; r.y = v1;
        r.z = __int_as_float(i0); r.w = __int_as_float(i1);
        final12[row] = r;
    }
}

// ------------------------------------------------------------------
// rescore_col: exact fp32 top-2 over 6 cands per column (wave per col)
// ------------------------------------------------------------------
__global__ __launch_bounds__(256) void rescore_col_kernel(
    const float* __restrict__ AT, const float* __restrict__ BT,
    const int* __restrict__ col6,
    int* __restrict__ nn21, float* __restrict__ ratio21)
{
    const int t = threadIdx.x;
    const int w = t >> 6, l = t & 63;
    const int col = blockIdx.x * 4 + w;    // 0..16383
    float4 rv = *(const float4*)(BT + ((size_t)col << 8) + l * 4);
    float v0 = -4.f, v1 = -4.f; int i0 = 0x7fffffff, i1 = 0x7fffffff;
    const int* __restrict__ cl = col6 + (size_t)col * 6;
#pragma unroll
    for (int j = 0; j < 6; ++j) {
        int idx = cl[j];
        float4 cv = *(const float4*)(AT + ((size_t)idx << 8) + l * 4);
        float d = rv.x * cv.x;
        d = fmaf(rv.y, cv.y, d);
        d = fmaf(rv.z, cv.z, d);
        d = fmaf(rv.w, cv.w, d);
#pragma unroll
        for (int m = 1; m < 64; m <<= 1) d += __shfl_xor(d, m, 64);
        if (d > v0 || (d == v0 && idx < i0)) {
            v1 = v0; i1 = i0; v0 = d; i0 = idx;
        } else if (d > v1 || (d == v1 && idx < i1)) {
            v1 = d; i1 = idx;
        }
    }
    if (l == 0) {
        nn21[col] = i0;
        float d0 = sqrtf(fmaxf(2.f - 2.f * v0, 1e-12f));
        float d1 = sqrtf(fmaxf(2.f - 2.f * v1, 1e-12f));
        ratio21[col] = d0 / (d1 + EPSF);
    }
}

// ------------------------------------------------------------------
// final: mutual check, ratio test, border mask
// ------------------------------------------------------------------
__global__ void final_kernel(const float4* __restrict__ final12,
                             const int* __restrict__ nn21,
                             const float* __restrict__ ratio21,
                             float* __restrict__ out) {
    int i = blockIdx.x * blockDim.x + threadIdx.x;  // 0..16383
    float4 a = final12[i];
    float d0 = sqrtf(fmaxf(2.f - 2.f * a.x, 1e-12f));
    float d1 = sqrtf(fmaxf(2.f - 2.f * a.y, 1e-12f));
    int nn = __float_as_int(a.z);
    float r12 = d0 / (d1 + EPSF);
    bool mutual = (nn21[nn] == i);
    float r = fmaxf(r12, ratio21[nn]);
    int xA = i & (WDIM - 1), yA = i >> 7;
    int xB = nn & (WDIM - 1), yB = nn >> 7;
    bool border = (xA == 0) || (xA == WDIM - 1) || (yA == 0) || (yA == WDIM - 1) ||
                  (xB == 0) || (xB == WDIM - 1) || (yB == 0) || (yB == WDIM - 1);
    bool valid = mutual && (r < 0.95f) && !border;
    out[2 * i]       = valid ? d0 : 0.f;
    out[2 * i + 1]   = valid ? d1 : 0.f;
    out[2 * NP + i]  = (float)nn;
    out[3 * NP + i]  = valid ? 1.f : 0.f;
}

extern "C" void kernel_launch(void* const* d_in, const int* in_sizes, int n_in,
                              void* d_out, int out_size, void* d_ws, size_t ws_size,
                              hipStream_t stream) {
    (void)in_sizes; (void)n_in; (void)out_size; (void)ws_size;
    const float* A = (const float*)d_in[0];
    const float* B = (const float*)d_in[1];
    float* out = (float*)d_out;

    char* ws = (char*)d_ws;
    float* AT = (float*)ws;                                          // 16 MB
    float* BT = AT + (size_t)NP * CH;                                // 16 MB
    unsigned short* Abf = (unsigned short*)(BT + (size_t)NP * CH);   // 8 MB
    unsigned short* Bbf = Abf + (size_t)NP * CH;                     // 8 MB
    unsigned* cand_row = (unsigned*)(Bbf + (size_t)NP * CH);         // 1.5 MB
    unsigned* cand_col = cand_row + (size_t)NP * 24;                 // 12.6 MB
    int* col6 = (int*)(cand_col + (size_t)NCOLSLOT * NP);            // 0.4 MB
    float4* final12 = (float4*)(col6 + (size_t)NP * 6);              // 256 KB
    int* nn21 = (int*)(final12 + NP);                                // 64 KB
    float* ratio21 = (float*)(nn21 + NP);                            // 64 KB

    prep_kernel<<<512, 256, 0, stream>>>(A, B, AT, BT, Abf, Bbf);
    simk_kernel<<<NRT * SPLITS, 256, 0, stream>>>(Abf, Bbf, cand_row, cand_col);
    mergecol_kernel<<<NP / 256, 256, 0, stream>>>(cand_col, col6);
    rescore_row_kernel<<<NP / 4, 256, 0, stream>>>(AT, BT, cand_row, final12);
    rescore_col_kernel<<<NP / 4, 256, 0, stream>>>(AT, BT, col6, nn21, ratio21);
    final_kernel<<<NP / 256, 256, 0, stream>>>(final12, nn21, ratio21, out);
}

// Round 15
// 262.260 us; speedup vs baseline: 1.2729x; 1.0677x over previous
//
#include <hip/hip_runtime.h>
#include <math.h>

#define NP 16384      // pixels per map (128*128)
#define CH 256        // channels (K)
#define WDIM 128
#define EPSF 1e-8f

#define CHUNK 32
#define SPLITS 8
#define CPS (NP / SPLITS)            // 2048 cols per split
#define NCHUNK (CPS / CHUNK)         // 64
#define ROWS 512                     // rows per block (8 waves x 64)
#define NRT (NP / ROWS)              // 32 row tiles
#define CHUNK_BYTES (CHUNK * CH * 2) // 16384
#define NCOLSLOT (NRT * 3)           // 96 col-candidate slots per column

typedef short short8 __attribute__((ext_vector_type(8)));
typedef float floatx4 __attribute__((ext_vector_type(4)));

typedef __attribute__((address_space(1))) const unsigned int gu32;
typedef __attribute__((address_space(3))) unsigned int lu32;

#define NEG_INF_F __int_as_float(0xFF800000)
#define ROWKEY_MASK 0xFFFFF800u      // 21-bit sim | 11-bit local col

// ------------------------------------------------------------------
// prep: per-pixel 1/||d||, fp32 normalized transposed [pix][256],
// bf16 normalized swizzled (element ch stored at ch ^ ((pix&7)<<3))
// ------------------------------------------------------------------
__global__ __launch_bounds__(256) void prep_kernel(
    const float* __restrict__ A, const float* __restrict__ B,
    float* __restrict__ AT, float* __restrict__ BT,
    unsigned short* __restrict__ Abf, unsigned short* __restrict__ Bbf)
{
    __shared__ float tile[64 * 257];
    __shared__ float rnv[64];
    const int bid = blockIdx.x;
    const float* __restrict__ src = (bid < 256) ? A : B;
    float* __restrict__ dstT = (bid < 256) ? AT : BT;
    unsigned short* __restrict__ dstb = (bid < 256) ? Abf : Bbf;
    const int pixBase = (bid & 255) * 64;
    const int t = threadIdx.x;

    for (int k = 0; k < 64 * 256; k += 256) {
        int idx = k + t;
        int p = idx & 63;
        int c = idx >> 6;
        tile[p * 257 + c] = src[(size_t)c * NP + pixBase + p];
    }
    __syncthreads();
    if (t < 64) {
        float s = 0.f;
        for (int c = 0; c < 256; ++c) { float v = tile[t * 257 + c]; s = fmaf(v, v, s); }
        rnv[t] = 1.0f / sqrtf(s);
    }
    __syncthreads();
    for (int k = 0; k < 64 * 256; k += 256) {
        int idx = k + t;
        int p = idx >> 8;
        int c = idx & 255;
        dstT[((size_t)(pixBase + p) << 8) + c] = tile[p * 257 + c] * rnv[p];
    }
    for (int k = 0; k < 64 * 128; k += 256) {
        int idx = k + t;
        int p = idx >> 7;
        int c2 = (idx & 127) * 2;
        float rn = rnv[p];
        float v0 = tile[p * 257 + c2] * rn;
        float v1 = tile[p * 257 + c2 + 1] * rn;
        unsigned u0 = __float_as_uint(v0); u0 = (u0 + 0x7fffu + ((u0 >> 16) & 1u)) >> 16;
        unsigned u1 = __float_as_uint(v1); u1 = (u1 + 0x7fffu + ((u1 >> 16) & 1u)) >> 16;
        unsigned sw = ((unsigned)(p & 7)) << 3;
        int e = ((pixBase + p) << 8) + (c2 ^ (int)sw);
        *(unsigned*)(dstb + e) = (u0 & 0xffffu) | (u1 << 16);
    }
}

// ------------------------------------------------------------------
// simk ONE-PASS, 512-row blocks (8 waves x 64 rows/wave), 1 barrier
// per chunk. Rows/wave unchanged vs R14 (per-row cost identical);
// the 16KB col-staging chunk now serves 512 rows -> per-sim staging
// traffic, col HBM re-reads, and barrier instances all halve.
// Col path per chunk: per-lane sorted pair -> wave-private cbw[w]
// (same-wave DS in-order, no barrier) -> 2 lanes/col top-2 of 16
// -> colwave dbuf (16 partials/col) -> deferred MERGE2 (t<32):
// block top-3/col -> cand_col. Rows (A) = B-operand in regs (pinned).
// ------------------------------------------------------------------
__global__ __launch_bounds__(512, 2) void simk_kernel(
    const unsigned short* __restrict__ Abf, const unsigned short* __restrict__ Bbf,
    unsigned* __restrict__ cand_row, unsigned* __restrict__ cand_col)
{
    __shared__ __align__(16) char smem[2 * CHUNK_BYTES];      // 32 KB staging
    __shared__ __align__(16) float2 cbw[8][32 * 17 + 4];      // 35 KB wave-private
    __shared__ __align__(16) float2 colwave[2][32][17];       // 8.7 KB dbuf
    const int bid = blockIdx.x;
    const int rt = bid >> 3;          // 0..31
    const int split = bid & 7;
    const int t = threadIdx.x;        // 0..511
    const int w = t >> 6;             // 0..7
    const int l = t & 63;
    const int l15 = l & 15, lhi = l >> 4;
    const int rowBase = rt * ROWS;
    const int colBase = split * CPS;

    // --- row-descriptor fragments (B-operand) from A, pinned ---
    short8 Bfr[4][8];
#pragma unroll
    for (int ni = 0; ni < 4; ++ni) {
        int pix = rowBase + w * 64 + ni * 16 + l15;
        const unsigned short* pr = Abf + ((size_t)pix << 8);
        int sw = (pix & 7) << 3;
#pragma unroll
        for (int kk = 0; kk < 8; ++kk) {
            int ke = kk * 32 + lhi * 8;
            Bfr[ni][kk] = *(const short8*)(pr + (ke ^ sw));
        }
    }
#pragma unroll
    for (int ni = 0; ni < 4; ++ni)
#pragma unroll
        for (int kk = 0; kk < 8; ++kk)
            asm volatile("" : "+v"(Bfr[ni][kk]));

    // --- LDS byte offsets for A-operand frags (mi=0; mi=1 is +8192) ---
    int aoff[8];
    {
        int cp = l15;
        int sw = (cp & 7) << 3;
#pragma unroll
        for (int kk = 0; kk < 8; ++kk) {
            int ke = kk * 32 + lhi * 8;
            aoff[kk] = (cp * 256 + (ke ^ sw)) * 2;
        }
    }

    // row running top-2 per (mi, ni) stream — split by mi for ILP
    float tv0[2][4], tv1[2][4];
#pragma unroll
    for (int mi = 0; mi < 2; ++mi)
#pragma unroll
        for (int ni = 0; ni < 4; ++ni) { tv0[mi][ni] = NEG_INF_F; tv1[mi][ni] = NEG_INF_F; }

    const char* gbase = (const char*)(Bbf + ((size_t)colBase << 8));
    const floatx4 fzero = {0.f, 0.f, 0.f, 0.f};
    floatx4 acc[2][4];

#define STAGE(CIDX, BUFSEL) do {                                              \
        const char* gsrc_ = gbase + (size_t)(CIDX) * CHUNK_BYTES;             \
        char* bdst_ = smem + (BUFSEL) * CHUNK_BYTES;                          \
        _Pragma("unroll")                                                     \
        for (int r_ = 0; r_ < 2; ++r_) {                                      \
            int off_ = w * 2048 + r_ * 1024;                                  \
            __builtin_amdgcn_global_load_lds((gu32*)(gsrc_ + off_ + l * 16),  \
                                             (lu32*)(bdst_ + off_), 16, 0, 0);\
        }                                                                     \
    } while (0)

#define MERGE2(CIDX) do {                                                     \
        if (t < 32) {                                                         \
            float b0_ = NEG_INF_F, b1_ = NEG_INF_F, b2_ = NEG_INF_F;          \
            _Pragma("unroll")                                                 \
            for (int j_ = 0; j_ < 16; ++j_) {                                 \
                float2 v_ = colwave[(CIDX) & 1][t][j_];                       \
                float k_ = v_.x, h_;                                          \
                h_ = fmaxf(b0_, k_); k_ = fminf(b0_, k_); b0_ = h_;           \
                h_ = fmaxf(b1_, k_); k_ = fminf(b1_, k_); b1_ = h_;           \
                b2_ = fmaxf(b2_, k_);                                         \
                k_ = v_.y;                                                    \
                h_ = fmaxf(b0_, k_); k_ = fminf(b0_, k_); b0_ = h_;           \
                h_ = fmaxf(b1_, k_); k_ = fminf(b1_, k_); b1_ = h_;           \
                b2_ = fmaxf(b2_, k_);                                         \
            }                                                                 \
            int colG_ = colBase + (CIDX) * 32 + t;                            \
            cand_col[(size_t)(rt * 3 + 0) * NP + colG_] = __float_as_uint(b0_);\
            cand_col[(size_t)(rt * 3 + 1) * NP + colG_] = __float_as_uint(b1_);\
            cand_col[(size_t)(rt * 3 + 2) * NP + colG_] = __float_as_uint(b2_);\
        }                                                                     \
    } while (0)

    STAGE(0, 0);

    for (int c = 0; c < NCHUNK; ++c) {
        __syncthreads();   // B1: staging(c) ready; colwave[(c-1)&1] published
        if (c + 1 < NCHUNK) STAGE(c + 1, (c + 1) & 1);
        if (c > 0) MERGE2(c - 1);

        // ---- COMPUTE: 64 MFMA into acc ----
        {
            const char* buf = smem + (c & 1) * CHUNK_BYTES;
            __builtin_amdgcn_s_setprio(1);
            {
                short8 a0 = *(const short8*)(buf + aoff[0]);
                short8 a1 = *(const short8*)(buf + aoff[0] + 8192);
#pragma unroll
                for (int ni = 0; ni < 4; ++ni) {
                    acc[0][ni] = __builtin_amdgcn_mfma_f32_16x16x32_bf16(a0, Bfr[ni][0], fzero, 0, 0, 0);
                    acc[1][ni] = __builtin_amdgcn_mfma_f32_16x16x32_bf16(a1, Bfr[ni][0], fzero, 0, 0, 0);
                }
            }
#pragma unroll
            for (int kk = 1; kk < 8; ++kk) {
                short8 a0 = *(const short8*)(buf + aoff[kk]);
                short8 a1 = *(const short8*)(buf + aoff[kk] + 8192);
#pragma unroll
                for (int ni = 0; ni < 4; ++ni) {
                    acc[0][ni] = __builtin_amdgcn_mfma_f32_16x16x32_bf16(a0, Bfr[ni][kk], acc[0][ni], 0, 0, 0);
                    acc[1][ni] = __builtin_amdgcn_mfma_f32_16x16x32_bf16(a1, Bfr[ni][kk], acc[1][ni], 0, 0, 0);
                }
            }
            __builtin_amdgcn_s_setprio(0);
        }

        // ---- COL extract: per-lane sorted pair of 4 rows -> cbw[w] ----
        {
            const unsigned brb = ((unsigned)w << 6) | (unsigned)l15;
#pragma unroll
            for (int mi = 0; mi < 2; ++mi) {
#pragma unroll
                for (int reg = 0; reg < 4; ++reg) {
                    unsigned k0 = (__float_as_uint(acc[mi][0][reg]) & 0xFFFFFE00u) | brb;
                    unsigned k1 = (__float_as_uint(acc[mi][1][reg]) & 0xFFFFFE00u) | (brb | 16u);
                    unsigned k2 = (__float_as_uint(acc[mi][2][reg]) & 0xFFFFFE00u) | (brb | 32u);
                    unsigned k3 = (__float_as_uint(acc[mi][3][reg]) & 0xFFFFFE00u) | (brb | 48u);
                    float f0 = __uint_as_float(k0), f1 = __uint_as_float(k1);
                    float f2 = __uint_as_float(k2), f3 = __uint_as_float(k3);
                    float h01 = fmaxf(f0, f1), l01 = fminf(f0, f1);
                    float h23 = fmaxf(f2, f3), l23 = fminf(f2, f3);
                    float hi = fmaxf(h01, h23);
                    float lo = fmaxf(fminf(h01, h23), fmaxf(l01, l23));
                    int colL = mi * 16 + lhi * 4 + reg;
                    cbw[w][colL * 17 + l15] = make_float2(hi, lo);
                }
            }
        }

        // ---- ROW top-2 (21-bit key | c*32 + col-local), mi-split chains ----
        {
            const int cS = c << 5;
#pragma unroll
            for (int mi = 0; mi < 2; ++mi) {
#pragma unroll
                for (int reg = 0; reg < 4; ++reg) {
                    const int ib = (lhi * 4 + mi * 16 + reg) | cS;
#pragma unroll
                    for (int ni = 0; ni < 4; ++ni) {
                        int kb = (__float_as_int(acc[mi][ni][reg]) & (int)ROWKEY_MASK) | ib;
                        float fk = __int_as_float(kb);
                        float h = fmaxf(tv0[mi][ni], fk);
                        float lo2 = fminf(tv0[mi][ni], fk);
                        tv0[mi][ni] = h;
                        tv1[mi][ni] = fmaxf(tv1[mi][ni], lo2);
                    }
                }
            }
        }

        // ---- wave merge (no barrier: same-wave DS ops are in-order):
        //      2 lanes/col read 8 pairs each -> top-2 of 16 -> colwave ----
        {
            int colR = l >> 1, half = l & 1;
            const float2* src = &cbw[w][colR * 17 + half * 8];
            float a = NEG_INF_F, b = NEG_INF_F;
#pragma unroll
            for (int j = 0; j < 8; ++j) {
                float2 v = src[j];
                float t0 = fmaxf(a, v.x);
                float t1 = fmaxf(fminf(a, v.x), fmaxf(b, v.y));
                a = t0; b = t1;
            }
            colwave[c & 1][colR][w * 2 + half] = make_float2(a, b);
        }
    }
    __syncthreads();       // publishes colwave[(NCHUNK-1)&1]; cbw free
    MERGE2(NCHUNK - 1);
#undef STAGE
#undef MERGE2

    // ---- final row merge: 16 keys per row -> top-3 keys per split ----
    int4* mrg = (int4*)cbw;        // [512 rows][4 lhi] int4 = 32 KB (cbw is 35)
#pragma unroll
    for (int ni = 0; ni < 4; ++ni) {
        int rloc = w * 64 + ni * 16 + l15;
        int4 p;
        p.x = __float_as_int(tv0[0][ni]);
        p.y = __float_as_int(tv1[0][ni]);
        p.z = __float_as_int(tv0[1][ni]);
        p.w = __float_as_int(tv1[1][ni]);
        mrg[rloc * 4 + lhi] = p;
    }
    __syncthreads();
    {
        float b0 = NEG_INF_F, b1 = NEG_INF_F, b2 = NEG_INF_F;
#pragma unroll
        for (int q = 0; q < 4; ++q) {
            int4 p = mrg[t * 4 + q];
            int ks[4] = {p.x, p.y, p.z, p.w};
#pragma unroll
            for (int j = 0; j < 4; ++j) {
                float k = __int_as_float(ks[j]), h;
                h = fmaxf(b0, k); k = fminf(b0, k); b0 = h;
                h = fmaxf(b1, k); k = fminf(b1, k); b1 = h;
                b2 = fmaxf(b2, k);
            }
        }
        int rowG = rowBase + t;
        unsigned* o = cand_row + (size_t)rowG * 24 + split * 3;
        o[0] = __float_as_uint(b0);
        o[1] = __float_as_uint(b1);
        o[2] = __float_as_uint(b2);
    }
}

// ------------------------------------------------------------------
// mergecol: per column, key top-6 of 96 block partials -> rows
// ------------------------------------------------------------------
__global__ __launch_bounds__(256) void mergecol_kernel(
    const unsigned* __restrict__ cand_col, int* __restrict__ col6)
{
    int col = blockIdx.x * 256 + threadIdx.x;   // 0..16383
    float bv0 = NEG_INF_F, bv1 = NEG_INF_F, bv2 = NEG_INF_F;
    float bv3 = NEG_INF_F, bv4 = NEG_INF_F, bv5 = NEG_INF_F;
    for (int s = 0; s < NCOLSLOT; ++s) {
        float k = __uint_as_float(cand_col[(size_t)s * NP + col]);
        float h;
        h = fmaxf(bv0, k); k = fminf(bv0, k); bv0 = h;
        h = fmaxf(bv1, k); k = fminf(bv1, k); bv1 = h;
        h = fmaxf(bv2, k); k = fminf(bv2, k); bv2 = h;
        h = fmaxf(bv3, k); k = fminf(bv3, k); bv3 = h;
        h = fmaxf(bv4, k); k = fminf(bv4, k); bv4 = h;
        bv5 = fmaxf(bv5, k);
    }
    const float thr = bv5;
    int r0 = 0, r1 = 0, r2 = 0, r3 = 0, r4 = 0, r5 = 0;
    int cnt = 0;
    for (int s = 0; s < NCOLSLOT; ++s) {
        unsigned ku = cand_col[(size_t)s * NP + col];
        float k = __uint_as_float(ku);
        bool take = (k >= thr) && (cnt < 6);
        int row = (s / 3) * ROWS + (int)(ku & 0x1FFu);
        r0 = (take && cnt == 0) ? row : r0;
        r1 = (take && cnt == 1) ? row : r1;
        r2 = (take && cnt == 2) ? row : r2;
        r3 = (take && cnt == 3) ? row : r3;
        r4 = (take && cnt == 4) ? row : r4;
        r5 = (take && cnt == 5) ? row : r5;
        cnt += take ? 1 : 0;
    }
    int* o = col6 + (size_t)col * 6;
    o[0] = r0; o[1] = r1; o[2] = r2; o[3] = r3; o[4] = r4; o[5] = r5;
}

// ------------------------------------------------------------------
// rescore_row: key-threshold top-8 of 24, then exact fp32 top-2
// (wave per row; branch is wave-uniform)
// ------------------------------------------------------------------
__global__ __launch_bounds__(256) void rescore_row_kernel(
    const float* __restrict__ AT, const float* __restrict__ BT,
    const unsigned* __restrict__ cand_row, float4* __restrict__ final12)
{
    const int t = threadIdx.x;
    const int w = t >> 6, l = t & 63;
    const int row = blockIdx.x * 4 + w;    // 0..16383
    float4 rv = *(const float4*)(AT + ((size_t)row << 8) + l * 4);
    const unsigned* __restrict__ cl = cand_row + (size_t)row * 24;

    // 8th-largest key (all lanes compute identically from broadcast loads)
    float t8[8];
#pragma unroll
    for (int q = 0; q < 8; ++q) t8[q] = NEG_INF_F;
#pragma unroll
    for (int s = 0; s < 24; ++s) {
        float k = __uint_as_float(cl[s]);
#pragma unroll
        for (int q = 0; q < 8; ++q) {
            float h = fmaxf(t8[q], k);
            k = fminf(t8[q], k);
            t8[q] = h;
        }
    }
    const float thr = t8[7];

    float v0 = -4.f, v1 = -4.f; int i0 = 0x7fffffff, i1 = 0x7fffffff;
    int taken = 0;
    for (int s = 0; s < 24; ++s) {
        unsigned ku = cl[s];
        float kf = __uint_as_float(ku);
        if (kf >= thr && taken < 8) {      // wave-uniform
            ++taken;
            int idx = (s / 3) * CPS + (int)(ku & 0x7FFu);
            float4 cv = *(const float4*)(BT + ((size_t)idx << 8) + l * 4);
            float d = rv.x * cv.x;
            d = fmaf(rv.y, cv.y, d);
            d = fmaf(rv.z, cv.z, d);
            d = fmaf(rv.w, cv.w, d);
#pragma unroll
            for (int m = 1; m < 64; m <<= 1) d += __shfl_xor(d, m, 64);
            if (d > v0 || (d == v0 && idx < i0)) {
                v1 = v0; i1 = i0; v0 = d; i0 = idx;
            } else if (d > v1 || (d == v1 && idx < i1)) {
                v1 = d; i1 = idx;
            }
        }
    }
    if (l == 0) {
        float4 r; r.x = v0; r.y = v1;
        r.z = __int_as_float(i0); r.w = __int_as_float(i1);
        final12[row] = r;
    }
}

// ------------------------------------------------------------------
// rescore_col: exact fp32 top-2 over 6 cands per column (wave per col)
// ------------------------------------------------------------------
__global__ __launch_bounds__(256) void rescore_col_kernel(
    const float* __restrict__ AT, const float* __restrict__ BT,
    const int* __restrict__ col6,
    int* __restrict__ nn21, float* __restrict__ ratio21)
{
    const int t = threadIdx.x;
    const int w = t >> 6, l = t & 63;
    const int col = blockIdx.x * 4 + w;    // 0..16383
    float4 rv = *(const float4*)(BT + ((size_t)col << 8) + l * 4);
    float v0 = -4.f, v1 = -4.f; int i0 = 0x7fffffff, i1 = 0x7fffffff;
    const int* __restrict__ cl = col6 + (size_t)col * 6;
#pragma unroll
    for (int j = 0; j < 6; ++j) {
        int idx = cl[j];
        float4 cv = *(const float4*)(AT + ((size_t)idx << 8) + l * 4);
        float d = rv.x * cv.x;
        d = fmaf(rv.y, cv.y, d);
        d = fmaf(rv.z, cv.z, d);
        d = fmaf(rv.w, cv.w, d);
#pragma unroll
        for (int m = 1; m < 64; m <<= 1) d += __shfl_xor(d, m, 64);
        if (d > v0 || (d == v0 && idx < i0)) {
            v1 = v0; i1 = i0; v0 = d; i0 = idx;
        } else if (d > v1 || (d == v1 && idx < i1)) {
            v1 = d; i1 = idx;
        }
    }
    if (l == 0) {
        nn21[col] = i0;
        float d0 = sqrtf(fmaxf(2.f - 2.f * v0, 1e-12f));
        float d1 = sqrtf(fmaxf(2.f - 2.f * v1, 1e-12f));
        ratio21[col] = d0 / (d1 + EPSF);
    }
}

// ------------------------------------------------------------------
// final: mutual check, ratio test, border mask
// ------------------------------------------------------------------
__global__ void final_kernel(const float4* __restrict__ final12,
                             const int* __restrict__ nn21,
                             const float* __restrict__ ratio21,
                             float* __restrict__ out) {
    int i = blockIdx.x * blockDim.x + threadIdx.x;  // 0..16383
    float4 a = final12[i];
    float d0 = sqrtf(fmaxf(2.f - 2.f * a.x, 1e-12f));
    float d1 = sqrtf(fmaxf(2.f - 2.f * a.y, 1e-12f));
    int nn = __float_as_int(a.z);
    float r12 = d0 / (d1 + EPSF);
    bool mutual = (nn21[nn] == i);
    float r = fmaxf(r12, ratio21[nn]);
    int xA = i & (WDIM - 1), yA = i >> 7;
    int xB = nn & (WDIM - 1), yB = nn >> 7;
    bool border = (xA == 0) || (xA == WDIM - 1) || (yA == 0) || (yA == WDIM - 1) ||
                  (xB == 0) || (xB == WDIM - 1) || (yB == 0) || (yB == WDIM - 1);
    bool valid = mutual && (r < 0.95f) && !border;
    out[2 * i]       = valid ? d0 : 0.f;
    out[2 * i + 1]   = valid ? d1 : 0.f;
    out[2 * NP + i]  = (float)nn;
    out[3 * NP + i]  = valid ? 1.f : 0.f;
}

extern "C" void kernel_launch(void* const* d_in, const int* in_sizes, int n_in,
                              void* d_out, int out_size, void* d_ws, size_t ws_size,
                              hipStream_t stream) {
    (void)in_sizes; (void)n_in; (void)out_size; (void)ws_size;
    const float* A = (const float*)d_in[0];
    const float* B = (const float*)d_in[1];
    float* out = (float*)d_out;

    char* ws = (char*)d_ws;
    float* AT = (float*)ws;                                          // 16 MB
    float* BT = AT + (size_t)NP * CH;                                // 16 MB
    unsigned short* Abf = (unsigned short*)(BT + (size_t)NP * CH);   // 8 MB
    unsigned short* Bbf = Abf + (size_t)NP * CH;                     // 8 MB
    unsigned* cand_row = (unsigned*)(Bbf + (size_t)NP * CH);         // 1.5 MB
    unsigned* cand_col = cand_row + (size_t)NP * 24;                 // 6.3 MB
    int* col6 = (int*)(cand_col + (size_t)NCOLSLOT * NP);            // 0.4 MB
    float4* final12 = (float4*)(col6 + (size_t)NP * 6);              // 256 KB
    int* nn21 = (int*)(final12 + NP);                                // 64 KB
    float* ratio21 = (float*)(nn21 + NP);                            // 64 KB

    prep_kernel<<<512, 256, 0, stream>>>(A, B, AT, BT, Abf, Bbf);
    simk_kernel<<<NRT * SPLITS, 512, 0, stream>>>(Abf, Bbf, cand_row, cand_col);
    mergecol_kernel<<<NP / 256, 256, 0, stream>>>(cand_col, col6);
    rescore_row_kernel<<<NP / 4, 256, 0, stream>>>(AT, BT, cand_row, final12);
    rescore_col_kernel<<<NP / 4, 256, 0, stream>>>(AT, BT, col6, nn21, ratio21);
    final_kernel<<<NP / 256, 256, 0, stream>>>(final12, nn21, ratio21, out);
}